// Round 4
// baseline (410.423 us; speedup 1.0000x reference)
//
#include <hip/hip_runtime.h>
#include <hip/hip_bf16.h>

#define NB    4
#define HH    96
#define WW    96
#define PIX   9216
#define C0    324
#define MM    48
#define NROI  192
#define NPAIR 9216
#define KHEAD 6468
#define KRF   6272
#define SPLITS 28
#define CPS    7     // 28*7*32 = 6272

typedef unsigned short u16;
typedef __attribute__((ext_vector_type(8))) short bf16x8;
typedef __attribute__((ext_vector_type(4))) float f32x4;
typedef __attribute__((ext_vector_type(4))) unsigned short u16x4;
typedef __attribute__((ext_vector_type(4))) int i32x4;

__device__ __forceinline__ u16 f2bf(float f) {
    __hip_bfloat16 h = __float2bfloat16(f);
    union { __hip_bfloat16 h; u16 u; } c; c.h = h; return c.u;
}
__device__ __forceinline__ float b2f(u16 u) {
    union { unsigned int i; float f; } c; c.i = ((unsigned int)u) << 16; return c.f;
}

// ---------------------------------------------------------------------------
// Zero only the halo ring of act1p/act2p: 388 halo px * 256 ch * 4 img * 2 bufs
__global__ __launch_bounds__(256) void zero_halo(u16* __restrict__ a1, u16* __restrict__ a2)
{
    int idx = blockIdx.x * 256 + threadIdx.x;   // 99328 total
    int c8 = idx & 31;
    int t = idx >> 5;
    int h = t % 388, img = t / 388;             // img 0..7
    u16* base = (img & 4) ? a2 : a1;
    int b = img & 3;
    int y, x;
    if (h < 98)       { y = 0;  x = h; }
    else if (h < 196) { y = 97; x = h - 98; }
    else { int r = (h - 196) >> 1; x = ((h - 196) & 1) * 97; y = 1 + r; }
    long long off = (((long long)(b * 98 + y)) * 98 + x) * 256 + c8 * 8;
    i32x4 z = {0, 0, 0, 0};
    *(i32x4*)(base + off) = z;
}

// ---------------------------------------------------------------------------
// One merged prep dispatch (same layouts as before).
__global__ __launch_bounds__(256) void prep_all(
    const float* __restrict__ c1w, const float* __restrict__ c2w,
    const float* __restrict__ c3w, const float* __restrict__ hw,
    const float* __restrict__ f6w, const float* __restrict__ f7w,
    u16* __restrict__ wt1f, u16* __restrict__ wt2f, u16* __restrict__ wt3f,
    u16* __restrict__ wtHt, u16* __restrict__ w6c, u16* __restrict__ w7c,
    float* __restrict__ wsum4)
{
    int blk = blockIdx.x, tid = threadIdx.x;
    if (blk < 352) {
        int idx = blk * 256 + tid;            // 11*16*16*32 = 90112
        if (idx >= 90112) return;
        int kk = idx & 31, m = (idx >> 5) & 15, ot = (idx >> 9) & 15, kc = idx >> 13;
        int oc = ot * 16 + m, k = kc * 32 + kk;
        wt1f[idx] = f2bf((k < C0) ? c1w[oc * C0 + k] : 0.f);
    } else if (blk < 2656) {
        int idx = (blk - 352) * 256 + tid;    // 256*256*9
        int kk = idx & 31; int rest = idx >> 5;
        int m = rest & 15; rest >>= 4;
        int ot = rest & 15; rest >>= 4;
        int tap = rest % 9; int kc = rest / 9;
        wt2f[idx] = f2bf(c2w[((ot * 16 + m) * 256 + kc * 32 + kk) * 9 + tap]);
    } else if (blk < 3808) {
        int idx = (blk - 2656) * 256 + tid;   // 128*256*9
        int kk = idx & 31; int rest = idx >> 5;
        int m = rest & 15; rest >>= 4;
        int ot = rest & 7; rest >>= 3;
        int tap = rest % 9; int kc = rest / 9;
        wt3f[idx] = f2bf(c3w[((ot * 16 + m) * 256 + kc * 32 + kk) * 9 + tap]);
    } else if (blk < 10080) {
        int idx = (blk - 3808) * 256 + tid;   // 256*6272
        int oc = idx / KRF, r = idx % KRF;
        int s = r >> 7, c = r & 127;
        wtHt[idx] = f2bf(hw[oc * KHEAD + c * 49 + s]);
    } else if (blk < 10336) {
        int idx = (blk - 10080) * 256 + tid;
        w6c[idx] = f2bf(f6w[idx]);
    } else if (blk < 10592) {
        int idx = (blk - 10336) * 256 + tid;
        w7c[idx] = f2bf(f7w[idx]);
    } else {
        int idx = (blk - 10592) * 256 + tid;  // 1024
        if (idx >= 1024) return;
        int oc = idx >> 2, j = idx & 3;
        const float* p = hw + (long long)oc * KHEAD + (128 + j) * 49;
        float s = 0.f;
        #pragma unroll
        for (int t = 0; t < 49; ++t) s += p[t];
        wsum4[idx] = s;
    }
}

// ---------------------------------------------------------------------------
// conv1 (1x1, K=324->352) fused fp32 read + transpose + MFMA.
// Block 512 thr = 8 waves. Tile 64 px x 256 oc. Grid (144, 4).
// Staging per kc: 64px x 32k fp32, one float4 per thread, LDS transpose.
__global__ __launch_bounds__(512) void conv1_mfma(
    const float* __restrict__ corr, const u16* __restrict__ wf,
    const float* __restrict__ bias, u16* __restrict__ outp)
{
    __shared__ __align__(16) u16 Bs[64 * 40];
    const int tid = threadIdx.x;
    const int b = blockIdx.y;
    const int p0 = blockIdx.x * 64;
    const int lane = tid & 63, wid = tid >> 6;
    const int q = lane >> 4, m16 = lane & 15;
    const int woc = wid & 3, wpx = wid >> 2;
    const int fragoff = m16 * 4 + q;
    const bf16x8* W8 = (const bf16x8*)wf;

    const int kr = tid >> 4, pxg = tid & 15;   // kr 0..31, pxg 0..15

    f32x4 acc[4][2];
    #pragma unroll
    for (int i = 0; i < 4; ++i)
        #pragma unroll
        for (int j = 0; j < 2; ++j) acc[i][j] = (f32x4){0.f, 0.f, 0.f, 0.f};

    float4 stg = {0.f, 0.f, 0.f, 0.f};
    if (kr < C0)
        stg = *(const float4*)&corr[((long long)(b * C0 + kr)) * PIX + p0 + pxg * 4];
    for (int kc = 0; kc < 11; ++kc) {
        __syncthreads();
        Bs[(pxg * 4 + 0) * 40 + kr] = f2bf(stg.x);
        Bs[(pxg * 4 + 1) * 40 + kr] = f2bf(stg.y);
        Bs[(pxg * 4 + 2) * 40 + kr] = f2bf(stg.z);
        Bs[(pxg * 4 + 3) * 40 + kr] = f2bf(stg.w);
        __syncthreads();
        if (kc < 10) {
            int k = (kc + 1) * 32 + kr;
            if (k < C0) stg = *(const float4*)&corr[((long long)(b * C0 + k)) * PIX + p0 + pxg * 4];
            else        stg = (float4){0.f, 0.f, 0.f, 0.f};
        }
        bf16x8 a[4], bb[2];
        #pragma unroll
        for (int i = 0; i < 4; ++i)
            a[i] = W8[(kc * 16 + woc * 4 + i) * 64 + fragoff];
        #pragma unroll
        for (int pt = 0; pt < 2; ++pt)
            bb[pt] = *(const bf16x8*)&Bs[(wpx * 32 + pt * 16 + m16) * 40 + q * 8];
        #pragma unroll
        for (int i = 0; i < 4; ++i)
            #pragma unroll
            for (int pt = 0; pt < 2; ++pt)
                acc[i][pt] = __builtin_amdgcn_mfma_f32_16x16x32_bf16(a[i], bb[pt], acc[i][pt], 0, 0, 0);
    }
    #pragma unroll
    for (int i = 0; i < 4; ++i) {
        int oc4 = woc * 64 + i * 16 + q * 4;
        f32x4 bv = *(const f32x4*)(bias + oc4);
        #pragma unroll
        for (int pt = 0; pt < 2; ++pt) {
            int p = p0 + wpx * 32 + pt * 16 + m16;
            int y = p / 96, x = p % 96;
            f32x4 d = acc[i][pt];
            u16x4 pk;
            #pragma unroll
            for (int r = 0; r < 4; ++r) pk[r] = f2bf(fmaxf(d[r] + bv[r], 0.f));
            *(u16x4*)(outp + (((long long)(b * 98 + y + 1) * 98) + x + 1) * 256 + oc4) = pk;
        }
    }
}

// ---------------------------------------------------------------------------
// conv3x3 MFMA implicit GEMM. Tile: 128 oc x (TR rows x 16 cols).
// 4 waves: wave = 64 oc x (TR/2 rows x 16 cols). Halo (TR+2) x 18.
template<int COUT, int TR, bool PADOUT>
__global__ __launch_bounds__(256) void conv3x3_mfma(
    const u16* __restrict__ inp, const u16* __restrict__ wf,
    const float* __restrict__ bias, u16* __restrict__ outp)
{
    const int RPW = TR / 2;          // rows per wave
    const int NH  = (TR + 2) * 18;   // halo pixels
    __shared__ __align__(16) u16 Bs[NH * 40];
    const int OCT = COUT / 16;
    const int tid = threadIdx.x;
    const int b = blockIdx.z;
    const int x0 = (blockIdx.x % 6) * 16, y0 = (blockIdx.x / 6) * TR;
    const int lane = tid & 63, wid = tid >> 6;
    const int q = lane >> 4, m16 = lane & 15;
    const int woc = wid & 1, wpx = wid >> 1;
    const int fragoff = m16 * 4 + q;
    const bf16x8* W8 = (const bf16x8*)wf;

    const bool stager = (tid < NH);
    const int rowh = tid / 18, colh = tid % 18;
    const u16* sbase = inp + ((((long long)(b * 98 + y0 + rowh)) * 98 + x0 + colh) * 256);

    f32x4 acc[4][RPW];
    #pragma unroll
    for (int i = 0; i < 4; ++i)
        #pragma unroll
        for (int j = 0; j < RPW; ++j) acc[i][j] = (f32x4){0.f, 0.f, 0.f, 0.f};

    bf16x8 r0, r1, r2, r3;
    if (stager) {
        r0 = *(const bf16x8*)(sbase + 0);
        r1 = *(const bf16x8*)(sbase + 8);
        r2 = *(const bf16x8*)(sbase + 16);
        r3 = *(const bf16x8*)(sbase + 24);
    }
    for (int kc = 0; kc < 8; ++kc) {
        __syncthreads();
        if (stager) {
            *(bf16x8*)&Bs[tid * 40 + 0]  = r0;
            *(bf16x8*)&Bs[tid * 40 + 8]  = r1;
            *(bf16x8*)&Bs[tid * 40 + 16] = r2;
            *(bf16x8*)&Bs[tid * 40 + 24] = r3;
        }
        __syncthreads();
        if (kc < 7 && stager) {
            const u16* s = sbase + (kc + 1) * 32;
            r0 = *(const bf16x8*)(s + 0);
            r1 = *(const bf16x8*)(s + 8);
            r2 = *(const bf16x8*)(s + 16);
            r3 = *(const bf16x8*)(s + 24);
        }
        #pragma unroll
        for (int tap = 0; tap < 9; ++tap) {
            const int dy = tap / 3, dx = tap % 3;
            bf16x8 a[4], bb[RPW];
            #pragma unroll
            for (int i = 0; i < 4; ++i) {
                int otg = blockIdx.y * 8 + woc * 4 + i;
                a[i] = W8[(size_t)((kc * 9 + tap) * OCT + otg) * 64 + fragoff];
            }
            #pragma unroll
            for (int r = 0; r < RPW; ++r)
                bb[r] = *(const bf16x8*)&Bs[((wpx * RPW + r + dy) * 18 + m16 + dx) * 40 + q * 8];
            #pragma unroll
            for (int i = 0; i < 4; ++i)
                #pragma unroll
                for (int r = 0; r < RPW; ++r)
                    acc[i][r] = __builtin_amdgcn_mfma_f32_16x16x32_bf16(a[i], bb[r], acc[i][r], 0, 0, 0);
        }
    }
    #pragma unroll
    for (int i = 0; i < 4; ++i) {
        int oc4 = blockIdx.y * 128 + woc * 64 + i * 16 + q * 4;
        f32x4 bv = *(const f32x4*)(bias + oc4);
        #pragma unroll
        for (int r = 0; r < RPW; ++r) {
            int y = y0 + wpx * RPW + r;
            int x = x0 + m16;
            f32x4 d = acc[i][r];
            u16x4 pk;
            #pragma unroll
            for (int rg = 0; rg < 4; ++rg) pk[rg] = f2bf(fmaxf(d[rg] + bv[rg], 0.f));
            long long dst;
            if (PADOUT) dst = (((long long)(b * 98 + y + 1) * 98) + x + 1) * COUT + oc4;
            else        dst = (((long long)(b * 96 + y) * 96) + x) * COUT + oc4;
            *(u16x4*)(outp + dst) = pk;
        }
    }
}

// ---------------------------------------------------------------------------
// ROI align: rel [4][96][96][128] bf16 -> rf [192][6272] bf16 (k' = s*128+c)
__global__ __launch_bounds__(256) void roi_align_cl(
    const u16* __restrict__ rel, const float* __restrict__ det1,
    u16* __restrict__ rf)
{
    const int roi = blockIdx.x, tid = threadIdx.x;
    const int c = tid & 127, sb = tid >> 7;
    const int b = roi / MM, m = roi % MM;
    const float* d = det1 + (long long)(b * MM + m) * 10;
    float cx = d[2], cy = d[3], w = d[4], h = d[5];
    float x1f = cx - w * 0.5f, y1f = cy - h * 0.5f;
    float x1 = x1f * 0.125f, y1 = y1f * 0.125f;
    float x2 = (x1f + w) * 0.125f, y2 = (y1f + h) * 0.125f;
    float bh = (y2 - y1) * (1.f / 7.f), bw = (x2 - x1) * (1.f / 7.f);
    const u16* fb = rel + (long long)b * PIX * 128 + c;
    for (int s = sb; s < 49; s += 2) {
        int i = s / 7, j = s % 7;
        float sum = 0.f;
        #pragma unroll
        for (int di = 0; di < 2; ++di) {
            float y = y1 + ((float)(2 * i + di) + 0.5f) * 0.5f * bh;
            y = fminf(fmaxf(y, 0.f), 95.f);
            int yy0 = (int)floorf(y);
            int yy1 = min(yy0 + 1, 95);
            float wy = y - (float)yy0;
            #pragma unroll
            for (int dj = 0; dj < 2; ++dj) {
                float x = x1 + ((float)(2 * j + dj) + 0.5f) * 0.5f * bw;
                x = fminf(fmaxf(x, 0.f), 95.f);
                int xx0 = (int)floorf(x);
                int xx1 = min(xx0 + 1, 95);
                float wx = x - (float)xx0;
                float f00 = b2f(fb[((long long)yy0 * 96 + xx0) * 128]);
                float f01 = b2f(fb[((long long)yy0 * 96 + xx1) * 128]);
                float f10 = b2f(fb[((long long)yy1 * 96 + xx0) * 128]);
                float f11 = b2f(fb[((long long)yy1 * 96 + xx1) * 128]);
                sum += f00 * (1.f - wy) * (1.f - wx) + f01 * (1.f - wy) * wx
                     + f10 * wy * (1.f - wx) + f11 * wy * wx;
            }
        }
        rf[(long long)roi * KRF + s * 128 + c] = f2bf(sum * 0.25f);
    }
}

// ---------------------------------------------------------------------------
// Head GEMM split-K (28 splits x 7 chunks). Block 64 rois x 128 oc. Grid (6,28).
__global__ __launch_bounds__(256) void head_gemm_mfma(
    const u16* __restrict__ rf, const u16* __restrict__ wtHt,
    float* __restrict__ Gpart)
{
    __shared__ __align__(16) u16 As[64 * 40];
    __shared__ __align__(16) u16 Bs[128 * 40];
    const int tid = threadIdx.x;
    const int rb = blockIdx.x >> 1, ob = blockIdx.x & 1;
    const int split = blockIdx.y;
    const int lane = tid & 63, wid = tid >> 6;
    const int q = lane >> 4, m16 = lane & 15;
    const int wr = wid & 1, wo = wid >> 1;

    const int arl = tid >> 2, aqd = tid & 3;
    const u16* abase = rf + (long long)(rb * 64 + arl) * KRF + aqd * 8;
    const int bol0 = tid >> 2, bqd = tid & 3;
    const u16* bbase0 = wtHt + (long long)(ob * 128 + bol0) * KRF + bqd * 8;
    const u16* bbase1 = bbase0 + 64LL * KRF;

    f32x4 acc[2][4];
    #pragma unroll
    for (int i = 0; i < 2; ++i)
        #pragma unroll
        for (int j = 0; j < 4; ++j) acc[i][j] = (f32x4){0.f, 0.f, 0.f, 0.f};

    int k0 = split * CPS * 32;
    bf16x8 ra = *(const bf16x8*)(abase + k0);
    bf16x8 rb0 = *(const bf16x8*)(bbase0 + k0);
    bf16x8 rb1 = *(const bf16x8*)(bbase1 + k0);
    for (int cch = 0; cch < CPS; ++cch) {
        __syncthreads();
        *(bf16x8*)&As[arl * 40 + aqd * 8] = ra;
        *(bf16x8*)&Bs[bol0 * 40 + bqd * 8] = rb0;
        *(bf16x8*)&Bs[(64 + bol0) * 40 + bqd * 8] = rb1;
        __syncthreads();
        if (cch < CPS - 1) {
            int kn = k0 + (cch + 1) * 32;
            ra  = *(const bf16x8*)(abase + kn);
            rb0 = *(const bf16x8*)(bbase0 + kn);
            rb1 = *(const bf16x8*)(bbase1 + kn);
        }
        bf16x8 a[2], bb[4];
        #pragma unroll
        for (int rt = 0; rt < 2; ++rt)
            a[rt] = *(const bf16x8*)&As[(wr * 32 + rt * 16 + m16) * 40 + q * 8];
        #pragma unroll
        for (int ot = 0; ot < 4; ++ot)
            bb[ot] = *(const bf16x8*)&Bs[(wo * 64 + ot * 16 + m16) * 40 + q * 8];
        #pragma unroll
        for (int rt = 0; rt < 2; ++rt)
            #pragma unroll
            for (int ot = 0; ot < 4; ++ot)
                acc[rt][ot] = __builtin_amdgcn_mfma_f32_16x16x32_bf16(a[rt], bb[ot], acc[rt][ot], 0, 0, 0);
    }
    #pragma unroll
    for (int rt = 0; rt < 2; ++rt)
        #pragma unroll
        for (int ot = 0; ot < 4; ++ot) {
            int oc = ob * 128 + wo * 64 + ot * 16 + m16;
            #pragma unroll
            for (int rg = 0; rg < 4; ++rg) {
                int roi = rb * 64 + wr * 32 + rt * 16 + q * 4 + rg;
                Gpart[((long long)split * NROI + roi) * 256 + oc] = acc[rt][ot][rg];
            }
        }
}

__global__ __launch_bounds__(256) void reduce_G_kernel(
    const float* __restrict__ Gpart, float* __restrict__ G)
{
    int idx = blockIdx.x * 256 + threadIdx.x;
    float s = 0.f;
    #pragma unroll
    for (int sp = 0; sp < SPLITS; ++sp) s += Gpart[(long long)sp * NROI * 256 + idx];
    G[idx] = s;
}

// ---------------------------------------------------------------------------
// Fused tail: pair geometry + build_X + fc6 + fc7 + cls. Block = 64 pairs.
#define PHS 272
__global__ __launch_bounds__(256) void pair_head(
    const float* __restrict__ G, const float* __restrict__ d1,
    const float* __restrict__ d2, const float* __restrict__ wsum4,
    const float* __restrict__ hb,
    const u16* __restrict__ w6, const float* __restrict__ b6,
    const u16* __restrict__ w7, const float* __restrict__ b7,
    const float* __restrict__ cw, const float* __restrict__ cb,
    float* __restrict__ scores, float* __restrict__ labels,
    float* __restrict__ valid)
{
    __shared__ __align__(16) u16 bufA[64 * PHS];
    __shared__ __align__(16) u16 bufB[64 * PHS];
    __shared__ float Gs[2][256];
    __shared__ float ps[64][4];
    __shared__ float clw[256];

    const int tid = threadIdx.x;
    const int p0 = blockIdx.x * 64;
    const int r0 = p0 / MM;
    const int lane = tid & 63, w = tid >> 6;
    const int q = lane >> 4, m16 = lane & 15;

    clw[tid] = cw[tid];
    #pragma unroll
    for (int l = 0; l < 2; ++l) {
        int idx = tid + l * 256;
        int rr = idx >> 8, col = idx & 255;
        Gs[rr][col] = G[min(r0 + rr, NROI - 1) * 256 + col];
    }
    if (tid < 64) {
        int pair = p0 + tid;
        int b = pair / (MM * MM); int rem = pair % (MM * MM);
        int m1 = rem / MM, m2 = rem % MM;
        const float* rA = d1 + (long long)(b * MM + m1) * 10;
        const float* rB = d2 + (long long)(b * MM + m2) * 10;
        float v1 = rA[0], id1 = rA[1], cxa = rA[2], cya = rA[3], wa = rA[4], ha = rA[5];
        float v2 = rB[0], id2 = rB[1], cxb = rB[2], cyb = rB[3], wb = rB[4], hbv = rB[5];
        const float eps = 1e-6f;
        float ax1 = cxa - wa * 0.5f, ay1 = cya - ha * 0.5f;
        float ax2 = ax1 + wa,        ay2 = ay1 + ha;
        float bx1 = cxb - wb * 0.5f, by1 = cyb - hbv * 0.5f;
        float bx2 = bx1 + wb,        by2 = by1 + hbv;
        float ccx1 = (ax1 + ax2) * 0.5f, ccy1 = (ay1 + ay2) * 0.5f;
        float ww1 = fmaxf(ax2 - ax1, eps), hh1 = fmaxf(ay2 - ay1, eps);
        float ccx2 = (bx1 + bx2) * 0.5f, ccy2 = (by1 + by2) * 0.5f;
        float ww2 = fmaxf(bx2 - bx1, eps), hh2 = fmaxf(by2 - by1, eps);
        ps[tid][0] = (ccx2 - ccx1) / ww1;
        ps[tid][1] = (ccy2 - ccy1) / hh1;
        ps[tid][2] = logf(ww2 / ww1);
        ps[tid][3] = logf(hh2 / hh1);
        labels[pair] = (id1 == id2) ? 1.f : 0.f;
        valid[pair]  = (v1 != -1.f && v2 != -1.f) ? 1.f : 0.f;
    }
    __syncthreads();

    // build X tile [64 px][256 oc] into bufA
    #pragma unroll
    for (int it = 0; it < 16; ++it) {
        int idx = tid + it * 256;            // 4096 = 64 px * 64 oc4
        int px = idx >> 6, o4 = (idx & 63) * 4;
        int rl = (p0 + px) / MM - r0;
        f32x4 g = *(const f32x4*)&Gs[rl][o4];
        f32x4 hv = *(const f32x4*)&hb[o4];
        f32x4 p4 = *(const f32x4*)&ps[px][0];
        u16x4 pk;
        #pragma unroll
        for (int j = 0; j < 4; ++j) {
            f32x4 w4 = *(const f32x4*)&wsum4[(o4 + j) * 4];
            float v = g[j] + hv[j] + p4[0] * w4[0] + p4[1] * w4[1] + p4[2] * w4[2] + p4[3] * w4[3];
            pk[j] = f2bf(v);
        }
        *(u16x4*)&bufA[px * PHS + o4] = pk;
    }
    __syncthreads();

    // fc6: bufA -> bufB, then fc7: bufB -> bufA
    #pragma unroll
    for (int layer = 0; layer < 2; ++layer) {
        const u16* wgt = layer ? w7 : w6;
        const float* bs = layer ? b7 : b6;
        const u16* src = layer ? bufB : bufA;
        u16* dst = layer ? bufA : bufB;
        f32x4 acc[4][4];
        #pragma unroll
        for (int i = 0; i < 4; ++i)
            #pragma unroll
            for (int j = 0; j < 4; ++j) acc[i][j] = (f32x4){0.f, 0.f, 0.f, 0.f};
        #pragma unroll
        for (int kc = 0; kc < 8; ++kc) {
            bf16x8 a[4], bb[4];
            #pragma unroll
            for (int i = 0; i < 4; ++i)
                a[i] = *(const bf16x8*)&wgt[(w * 64 + i * 16 + m16) * 256 + kc * 32 + q * 8];
            #pragma unroll
            for (int pt = 0; pt < 4; ++pt)
                bb[pt] = *(const bf16x8*)&src[(pt * 16 + m16) * PHS + kc * 32 + q * 8];
            #pragma unroll
            for (int i = 0; i < 4; ++i)
                #pragma unroll
                for (int pt = 0; pt < 4; ++pt)
                    acc[i][pt] = __builtin_amdgcn_mfma_f32_16x16x32_bf16(a[i], bb[pt], acc[i][pt], 0, 0, 0);
        }
        #pragma unroll
        for (int i = 0; i < 4; ++i) {
            int oc4 = w * 64 + i * 16 + q * 4;
            f32x4 bv = *(const f32x4*)(bs + oc4);
            #pragma unroll
            for (int pt = 0; pt < 4; ++pt) {
                int px = pt * 16 + m16;
                f32x4 dd = acc[i][pt];
                u16x4 pk;
                #pragma unroll
                for (int rg = 0; rg < 4; ++rg)
                    pk[rg] = f2bf(fmaxf(dd[rg] + bv[rg], 0.f));
                *(u16x4*)&dst[px * PHS + oc4] = pk;
            }
        }
        __syncthreads();
    }

    // cls from bufA (holds H2)
    {
        int px = tid >> 2, qq = tid & 3;
        float acc = 0.f;
        #pragma unroll
        for (int k8 = 0; k8 < 8; ++k8) {
            bf16x8 hv = *(const bf16x8*)&bufA[px * PHS + qq * 64 + k8 * 8];
            #pragma unroll
            for (int e = 0; e < 8; ++e)
                acc += b2f((u16)hv[e]) * clw[qq * 64 + k8 * 8 + e];
        }
        acc += __shfl_xor(acc, 1, 64);
        acc += __shfl_xor(acc, 2, 64);
        if (qq == 0) scores[p0 + px] = acc + cb[0];
    }
}

// ---------------------------------------------------------------------------
extern "C" void kernel_launch(void* const* d_in, const int* in_sizes, int n_in,
                              void* d_out, int out_size, void* d_ws, size_t ws_size,
                              hipStream_t stream) {
    const float* corr   = (const float*)d_in[0];
    const float* det1   = (const float*)d_in[2];
    const float* det2   = (const float*)d_in[3];
    const float* c1w    = (const float*)d_in[4];
    const float* c1b    = (const float*)d_in[5];
    const float* c2w    = (const float*)d_in[6];
    const float* c2b    = (const float*)d_in[7];
    const float* c3w    = (const float*)d_in[8];
    const float* c3b    = (const float*)d_in[9];
    const float* hw     = (const float*)d_in[10];
    const float* hbias  = (const float*)d_in[11];
    const float* f6w    = (const float*)d_in[12];
    const float* f6b    = (const float*)d_in[13];
    const float* f7w    = (const float*)d_in[14];
    const float* f7b    = (const float*)d_in[15];
    const float* clsw   = (const float*)d_in[16];
    const float* clsb   = (const float*)d_in[17];
    float* out = (float*)d_out;

    char* base = (char*)d_ws;
    auto alloc = [&](size_t bytes) { char* p = base; base += (bytes + 255) & ~(size_t)255; return p; };

    const size_t ACTP_BYTES = (size_t)NB * 98 * 98 * 256 * 2;
    u16*   act1p = (u16*)  alloc(ACTP_BYTES);
    u16*   act2p = (u16*)  alloc(ACTP_BYTES);
    u16*   rel   = (u16*)  alloc((size_t)NB * PIX * 128 * 2);
    u16*   wt1f  = (u16*)  alloc((size_t)11 * 16 * 512 * 2);
    u16*   wt2f  = (u16*)  alloc((size_t)8 * 9 * 16 * 512 * 2);
    u16*   wt3f  = (u16*)  alloc((size_t)8 * 9 * 8 * 512 * 2);
    u16*   wtHt  = (u16*)  alloc((size_t)256 * KRF * 2);
    u16*   w6c   = (u16*)  alloc(256 * 256 * 2);
    u16*   w7c   = (u16*)  alloc(256 * 256 * 2);
    float* wsum4 = (float*)alloc(256 * 4 * 4);
    u16*   rf    = (u16*)  alloc((size_t)NROI * KRF * 2);
    float* Gpart = (float*)alloc((size_t)SPLITS * NROI * 256 * 4);
    float* G     = (float*)alloc(NROI * 256 * 4);

    float* scores_out = out;
    float* labels_out = out + NPAIR;
    float* valid_out  = out + 2 * NPAIR;

    zero_halo<<<388, 256, 0, stream>>>(act1p, act2p);
    prep_all<<<10596, 256, 0, stream>>>(c1w, c2w, c3w, hw, f6w, f7w,
                                        wt1f, wt2f, wt3f, wtHt, w6c, w7c, wsum4);
    conv1_mfma<<<dim3(144, NB), 512, 0, stream>>>(corr, wt1f, c1b, act1p);
    conv3x3_mfma<256, 4, true><<<dim3(144, 2, NB), 256, 0, stream>>>(act1p, wt2f, c2b, act2p);
    conv3x3_mfma<128, 2, false><<<dim3(288, 1, NB), 256, 0, stream>>>(act2p, wt3f, c3b, rel);
    roi_align_cl<<<NROI, 256, 0, stream>>>(rel, det1, rf);
    head_gemm_mfma<<<dim3(6, SPLITS), 256, 0, stream>>>(rf, wtHt, Gpart);
    reduce_G_kernel<<<NROI, 256, 0, stream>>>(Gpart, G);
    pair_head<<<144, 256, 0, stream>>>(G, det1, det2, wsum4, hbias,
                                       w6c, f6b, w7c, f7b, clsw, clsb,
                                       scores_out, labels_out, valid_out);
}

// Round 5
// 319.476 us; speedup vs baseline: 1.2847x; 1.2847x over previous
//
#include <hip/hip_runtime.h>
#include <hip/hip_bf16.h>

#define NB    4
#define HH    96
#define WW    96
#define PIX   9216
#define C0    324
#define MM    48
#define NROI  192
#define NPAIR 9216
#define KHEAD 6468
#define KRF   6272
#define SPLITS 28
#define CPS    7     // 28*7*32 = 6272

// conv tap-pair weight tile: 5 ksteps x 8 octiles x 16 m x 40 kk(pad) per 16-ic stage
#define WSTAGE 25600

typedef unsigned short u16;
typedef __attribute__((ext_vector_type(8))) short bf16x8;
typedef __attribute__((ext_vector_type(4))) float f32x4;
typedef __attribute__((ext_vector_type(4))) unsigned short u16x4;
typedef __attribute__((ext_vector_type(4))) int i32x4;

__device__ __forceinline__ u16 f2bf(float f) {
    __hip_bfloat16 h = __float2bfloat16(f);
    union { __hip_bfloat16 h; u16 u; } c; c.h = h; return c.u;
}
__device__ __forceinline__ float b2f(u16 u) {
    union { unsigned int i; float f; } c; c.i = ((unsigned int)u) << 16; return c.f;
}

// ---------------------------------------------------------------------------
// Zero only the halo ring of act1p/act2p
__global__ __launch_bounds__(256) void zero_halo(u16* __restrict__ a1, u16* __restrict__ a2)
{
    int idx = blockIdx.x * 256 + threadIdx.x;   // 99328 total
    int c8 = idx & 31;
    int t = idx >> 5;
    int h = t % 388, img = t / 388;             // img 0..7
    u16* base = (img & 4) ? a2 : a1;
    int b = img & 3;
    int y, x;
    if (h < 98)       { y = 0;  x = h; }
    else if (h < 196) { y = 97; x = h - 98; }
    else { int r = (h - 196) >> 1; x = ((h - 196) & 1) * 97; y = 1 + r; }
    long long off = (((long long)(b * 98 + y)) * 98 + x) * 256 + c8 * 8;
    i32x4 z = {0, 0, 0, 0};
    *(i32x4*)(base + off) = z;
}

// ---------------------------------------------------------------------------
// Merged prep. Block ranges:
// [0,352) wt1 | [352,3552) wt2 | [3552,5152) wt3 | [5152,11424) wtH
// [11424,11680) w6 | [11680,11936) w7 | [11936,11940) wsum
// conv2/conv3 tap-pair layout: [ocb][icb16][s5][ot8][m16][kk40]
//   kk<32: tap = 2s + (kk>>4), ic = icb*16 + (kk&15); zero if tap>=9 or kk>=32
__global__ __launch_bounds__(256) void prep_all(
    const float* __restrict__ c1w, const float* __restrict__ c2w,
    const float* __restrict__ c3w, const float* __restrict__ hw,
    const float* __restrict__ f6w, const float* __restrict__ f7w,
    u16* __restrict__ wt1f, u16* __restrict__ wt2f, u16* __restrict__ wt3f,
    u16* __restrict__ wtHt, u16* __restrict__ w6c, u16* __restrict__ w7c,
    float* __restrict__ wsum4)
{
    int blk = blockIdx.x, tid = threadIdx.x;
    if (blk < 352) {
        int idx = blk * 256 + tid;            // 11*16*16*32 = 90112
        if (idx >= 90112) return;
        int kk = idx & 31, m = (idx >> 5) & 15, ot = (idx >> 9) & 15, kc = idx >> 13;
        int oc = ot * 16 + m, k = kc * 32 + kk;
        wt1f[idx] = f2bf((k < C0) ? c1w[oc * C0 + k] : 0.f);
    } else if (blk < 3552) {
        int idx = (blk - 352) * 256 + tid;    // < 819200
        int kk = idx % 40; int t = idx / 40;
        int m = t & 15; t >>= 4;
        int ot = t & 7; t >>= 3;
        int s = t % 5; t /= 5;
        int icb = t & 15; int ocb = t >> 4;
        int tap = 2 * s + (kk >> 4);
        float v = 0.f;
        if (kk < 32 && tap < 9) {
            int oc = ocb * 128 + ot * 16 + m;
            int ic = icb * 16 + (kk & 15);
            v = c2w[(oc * 256 + ic) * 9 + tap];
        }
        wt2f[idx] = f2bf(v);
    } else if (blk < 5152) {
        int idx = (blk - 3552) * 256 + tid;   // < 409600
        int kk = idx % 40; int t = idx / 40;
        int m = t & 15; t >>= 4;
        int ot = t & 7; t >>= 3;
        int s = t % 5; t /= 5;
        int icb = t;                          // 0..15
        int tap = 2 * s + (kk >> 4);
        float v = 0.f;
        if (kk < 32 && tap < 9) {
            int oc = ot * 16 + m;
            int ic = icb * 16 + (kk & 15);
            v = c3w[(oc * 256 + ic) * 9 + tap];
        }
        wt3f[idx] = f2bf(v);
    } else if (blk < 11424) {
        int idx = (blk - 5152) * 256 + tid;   // 256*6272
        int oc = idx / KRF, r = idx % KRF;
        int s = r >> 7, c = r & 127;
        wtHt[idx] = f2bf(hw[oc * KHEAD + c * 49 + s]);
    } else if (blk < 11680) {
        int idx = (blk - 11424) * 256 + tid;
        w6c[idx] = f2bf(f6w[idx]);
    } else if (blk < 11936) {
        int idx = (blk - 11680) * 256 + tid;
        w7c[idx] = f2bf(f7w[idx]);
    } else {
        int idx = (blk - 11936) * 256 + tid;  // 1024
        if (idx >= 1024) return;
        int oc = idx >> 2, j = idx & 3;
        const float* p = hw + (long long)oc * KHEAD + (128 + j) * 49;
        float s = 0.f;
        #pragma unroll
        for (int t = 0; t < 49; ++t) s += p[t];
        wsum4[idx] = s;
    }
}

// ---------------------------------------------------------------------------
// conv1 (1x1, K=324->352) fused fp32 read + transpose + MFMA, weights via LDS.
// Block 512 thr = 8 waves. Tile 64 px x 256 oc. Grid (144, 4).
__global__ __launch_bounds__(512) void conv1_mfma(
    const float* __restrict__ corr, const u16* __restrict__ wf,
    const float* __restrict__ bias, u16* __restrict__ outp)
{
    __shared__ __align__(16) u16 Ws1[8192];   // [ot16][m16][kk32] per kc
    __shared__ __align__(16) u16 Bs[64 * 40];
    const int tid = threadIdx.x;
    const int b = blockIdx.y;
    const int p0 = blockIdx.x * 64;
    const int lane = tid & 63, wid = tid >> 6;
    const int q = lane >> 4, m16 = lane & 15;
    const int woc = wid & 3, wpx = wid >> 2;

    const int kr = tid >> 4, pxg = tid & 15;   // kr 0..31, pxg 0..15

    f32x4 acc[4][2];
    #pragma unroll
    for (int i = 0; i < 4; ++i)
        #pragma unroll
        for (int j = 0; j < 2; ++j) acc[i][j] = (f32x4){0.f, 0.f, 0.f, 0.f};

    float4 stg = {0.f, 0.f, 0.f, 0.f};
    if (kr < C0)
        stg = *(const float4*)&corr[((long long)(b * C0 + kr)) * PIX + p0 + pxg * 4];
    bf16x8 wr0 = *(const bf16x8*)(wf + tid * 16);
    bf16x8 wr1 = *(const bf16x8*)(wf + tid * 16 + 8);

    for (int kc = 0; kc < 11; ++kc) {
        __syncthreads();
        Bs[(pxg * 4 + 0) * 40 + kr] = f2bf(stg.x);
        Bs[(pxg * 4 + 1) * 40 + kr] = f2bf(stg.y);
        Bs[(pxg * 4 + 2) * 40 + kr] = f2bf(stg.z);
        Bs[(pxg * 4 + 3) * 40 + kr] = f2bf(stg.w);
        *(bf16x8*)&Ws1[tid * 16]     = wr0;
        *(bf16x8*)&Ws1[tid * 16 + 8] = wr1;
        __syncthreads();
        if (kc < 10) {
            int k = (kc + 1) * 32 + kr;
            if (k < C0) stg = *(const float4*)&corr[((long long)(b * C0 + k)) * PIX + p0 + pxg * 4];
            else        stg = (float4){0.f, 0.f, 0.f, 0.f};
            const u16* wn = wf + (kc + 1) * 8192;
            wr0 = *(const bf16x8*)(wn + tid * 16);
            wr1 = *(const bf16x8*)(wn + tid * 16 + 8);
        }
        bf16x8 a[4], bb[2];
        #pragma unroll
        for (int i = 0; i < 4; ++i)
            a[i] = *(const bf16x8*)&Ws1[(woc * 4 + i) * 512 + m16 * 32 + q * 8];
        #pragma unroll
        for (int pt = 0; pt < 2; ++pt)
            bb[pt] = *(const bf16x8*)&Bs[(wpx * 32 + pt * 16 + m16) * 40 + q * 8];
        #pragma unroll
        for (int i = 0; i < 4; ++i)
            #pragma unroll
            for (int pt = 0; pt < 2; ++pt)
                acc[i][pt] = __builtin_amdgcn_mfma_f32_16x16x32_bf16(a[i], bb[pt], acc[i][pt], 0, 0, 0);
    }
    #pragma unroll
    for (int i = 0; i < 4; ++i) {
        int oc4 = woc * 64 + i * 16 + q * 4;
        f32x4 bv = *(const f32x4*)(bias + oc4);
        #pragma unroll
        for (int pt = 0; pt < 2; ++pt) {
            int p = p0 + wpx * 32 + pt * 16 + m16;
            int y = p / 96, x = p % 96;
            f32x4 d = acc[i][pt];
            u16x4 pk;
            #pragma unroll
            for (int r = 0; r < 4; ++r) pk[r] = f2bf(fmaxf(d[r] + bv[r], 0.f));
            *(u16x4*)(outp + (((long long)(b * 98 + y + 1) * 98) + x + 1) * 256 + oc4) = pk;
        }
    }
}

// ---------------------------------------------------------------------------
// conv3x3 tap-pair MFMA: 16-ic stages, MFMA K=32 = 2 taps x 16 ic (taps padded to 10).
// Block: 128 oc x (TR rows x 32 cols). 4 waves = 2 oc-halves x 2 row-halves.
// Weights AND halo staged to LDS with register prefetch. Grid (3*(96/TR), COUT/128, 4).
template<int COUT, int TR, bool PADOUT>
__global__ __launch_bounds__(256, 2) void conv3x3_tp(
    const u16* __restrict__ inp, const u16* __restrict__ wf,
    const float* __restrict__ bias, u16* __restrict__ outp)
{
    const int RPW = TR / 2;
    const int NHP = (TR + 2) * 34;            // halo pixels
    __shared__ __align__(16) u16 Ws[WSTAGE];  // [s5][ot8][m16][kk40]
    __shared__ __align__(16) u16 Hs[NHP * 20];// [row][col34][ic 16(+4 pad)]
    const int tid = threadIdx.x;
    const int b = blockIdx.z;
    const int x0 = (blockIdx.x % 3) * 32, y0 = (blockIdx.x / 3) * TR;
    const int lane = tid & 63, wid = tid >> 6;
    const int q = lane >> 4, m16 = lane & 15;
    const int woc = wid & 1, wpx = wid >> 1;

    const u16* wsrc = wf + (size_t)(blockIdx.y * 16) * WSTAGE;
    const bool hstager = tid < NHP;
    const int hrow = tid / 34, hcol = tid % 34;
    const u16* hsrc = inp + (((size_t)(b * 98 + y0 + hrow) * 98) + x0 + hcol) * 256;

    f32x4 acc[4][RPW * 2];
    #pragma unroll
    for (int i = 0; i < 4; ++i)
        #pragma unroll
        for (int j = 0; j < RPW * 2; ++j) acc[i][j] = (f32x4){0.f, 0.f, 0.f, 0.f};

    bf16x8 wreg[13];
    bf16x8 hreg0, hreg1;
    #pragma unroll
    for (int it = 0; it < 13; ++it) {
        int c = it * 256 + tid;
        if (c < 3200) wreg[it] = *(const bf16x8*)(wsrc + c * 8);
    }
    if (hstager) { hreg0 = *(const bf16x8*)(hsrc); hreg1 = *(const bf16x8*)(hsrc + 8); }

    for (int icb = 0; icb < 16; ++icb) {
        __syncthreads();
        #pragma unroll
        for (int it = 0; it < 13; ++it) {
            int c = it * 256 + tid;
            if (c < 3200) *(bf16x8*)&Ws[c * 8] = wreg[it];
        }
        if (hstager) {
            *(bf16x8*)&Hs[tid * 20]     = hreg0;
            *(bf16x8*)&Hs[tid * 20 + 8] = hreg1;
        }
        __syncthreads();
        if (icb < 15) {
            const u16* wn = wsrc + (size_t)(icb + 1) * WSTAGE;
            #pragma unroll
            for (int it = 0; it < 13; ++it) {
                int c = it * 256 + tid;
                if (c < 3200) wreg[it] = *(const bf16x8*)(wn + c * 8);
            }
            if (hstager) {
                const u16* hn = hsrc + (icb + 1) * 16;
                hreg0 = *(const bf16x8*)(hn);
                hreg1 = *(const bf16x8*)(hn + 8);
            }
        }
        // compute: 5 ksteps, each K=32 = taps (2s, 2s+1[->8]) x 16 ic
        #pragma unroll
        for (int s = 0; s < 5; ++s) {
            const int tapA = 2 * s;
            const int tapB = (s == 4) ? 8 : (2 * s + 1);
            const int dyA = tapA / 3, dxA = tapA % 3;
            const int dyB = tapB / 3, dxB = tapB % 3;
            int dy = (q >= 2) ? dyB : dyA;
            int dx = (q >= 2) ? dxB : dxA;
            int hb = (dy * 34 + dx) * 20 + (q & 1) * 8;
            bf16x8 a[4], bb[RPW * 2];
            #pragma unroll
            for (int i = 0; i < 4; ++i)
                a[i] = *(const bf16x8*)&Ws[((s * 8 + woc * 4 + i) * 16 + m16) * 40 + q * 8];
            #pragma unroll
            for (int r = 0; r < RPW; ++r)
                #pragma unroll
                for (int ct = 0; ct < 2; ++ct)
                    bb[r * 2 + ct] = *(const bf16x8*)&Hs[hb + ((wpx * RPW + r) * 34 + ct * 16 + m16) * 20];
            #pragma unroll
            for (int i = 0; i < 4; ++i)
                #pragma unroll
                for (int j = 0; j < RPW * 2; ++j)
                    acc[i][j] = __builtin_amdgcn_mfma_f32_16x16x32_bf16(a[i], bb[j], acc[i][j], 0, 0, 0);
        }
    }
    #pragma unroll
    for (int i = 0; i < 4; ++i) {
        int oc4 = blockIdx.y * 128 + woc * 64 + i * 16 + q * 4;
        f32x4 bv = *(const f32x4*)(bias + oc4);
        #pragma unroll
        for (int r = 0; r < RPW; ++r) {
            int y = y0 + wpx * RPW + r;
            #pragma unroll
            for (int ct = 0; ct < 2; ++ct) {
                int x = x0 + ct * 16 + m16;
                f32x4 d = acc[i][r * 2 + ct];
                u16x4 pk;
                #pragma unroll
                for (int rg = 0; rg < 4; ++rg) pk[rg] = f2bf(fmaxf(d[rg] + bv[rg], 0.f));
                long long dst;
                if (PADOUT) dst = (((long long)(b * 98 + y + 1) * 98) + x + 1) * COUT + oc4;
                else        dst = (((long long)(b * 96 + y) * 96) + x) * COUT + oc4;
                *(u16x4*)(outp + dst) = pk;
            }
        }
    }
}

// ---------------------------------------------------------------------------
// ROI align: rel [4][96][96][128] bf16 -> rf [192][6272] bf16 (k' = s*128+c)
__global__ __launch_bounds__(256) void roi_align_cl(
    const u16* __restrict__ rel, const float* __restrict__ det1,
    u16* __restrict__ rf)
{
    const int roi = blockIdx.x, tid = threadIdx.x;
    const int c = tid & 127, sb = tid >> 7;
    const int b = roi / MM, m = roi % MM;
    const float* d = det1 + (long long)(b * MM + m) * 10;
    float cx = d[2], cy = d[3], w = d[4], h = d[5];
    float x1f = cx - w * 0.5f, y1f = cy - h * 0.5f;
    float x1 = x1f * 0.125f, y1 = y1f * 0.125f;
    float x2 = (x1f + w) * 0.125f, y2 = (y1f + h) * 0.125f;
    float bh = (y2 - y1) * (1.f / 7.f), bw = (x2 - x1) * (1.f / 7.f);
    const u16* fb = rel + (long long)b * PIX * 128 + c;
    for (int s = sb; s < 49; s += 2) {
        int i = s / 7, j = s % 7;
        float sum = 0.f;
        #pragma unroll
        for (int di = 0; di < 2; ++di) {
            float y = y1 + ((float)(2 * i + di) + 0.5f) * 0.5f * bh;
            y = fminf(fmaxf(y, 0.f), 95.f);
            int yy0 = (int)floorf(y);
            int yy1 = min(yy0 + 1, 95);
            float wy = y - (float)yy0;
            #pragma unroll
            for (int dj = 0; dj < 2; ++dj) {
                float x = x1 + ((float)(2 * j + dj) + 0.5f) * 0.5f * bw;
                x = fminf(fmaxf(x, 0.f), 95.f);
                int xx0 = (int)floorf(x);
                int xx1 = min(xx0 + 1, 95);
                float wx = x - (float)xx0;
                float f00 = b2f(fb[((long long)yy0 * 96 + xx0) * 128]);
                float f01 = b2f(fb[((long long)yy0 * 96 + xx1) * 128]);
                float f10 = b2f(fb[((long long)yy1 * 96 + xx0) * 128]);
                float f11 = b2f(fb[((long long)yy1 * 96 + xx1) * 128]);
                sum += f00 * (1.f - wy) * (1.f - wx) + f01 * (1.f - wy) * wx
                     + f10 * wy * (1.f - wx) + f11 * wy * wx;
            }
        }
        rf[(long long)roi * KRF + s * 128 + c] = f2bf(sum * 0.25f);
    }
}

// ---------------------------------------------------------------------------
// Head GEMM split-K (28 splits x 7 chunks). Block 64 rois x 128 oc. Grid (6,28).
__global__ __launch_bounds__(256) void head_gemm_mfma(
    const u16* __restrict__ rf, const u16* __restrict__ wtHt,
    float* __restrict__ Gpart)
{
    __shared__ __align__(16) u16 As[64 * 40];
    __shared__ __align__(16) u16 Bs[128 * 40];
    const int tid = threadIdx.x;
    const int rb = blockIdx.x >> 1, ob = blockIdx.x & 1;
    const int split = blockIdx.y;
    const int lane = tid & 63, wid = tid >> 6;
    const int q = lane >> 4, m16 = lane & 15;
    const int wr = wid & 1, wo = wid >> 1;

    const int arl = tid >> 2, aqd = tid & 3;
    const u16* abase = rf + (long long)(rb * 64 + arl) * KRF + aqd * 8;
    const int bol0 = tid >> 2, bqd = tid & 3;
    const u16* bbase0 = wtHt + (long long)(ob * 128 + bol0) * KRF + bqd * 8;
    const u16* bbase1 = bbase0 + 64LL * KRF;

    f32x4 acc[2][4];
    #pragma unroll
    for (int i = 0; i < 2; ++i)
        #pragma unroll
        for (int j = 0; j < 4; ++j) acc[i][j] = (f32x4){0.f, 0.f, 0.f, 0.f};

    int k0 = split * CPS * 32;
    bf16x8 ra = *(const bf16x8*)(abase + k0);
    bf16x8 rb0 = *(const bf16x8*)(bbase0 + k0);
    bf16x8 rb1 = *(const bf16x8*)(bbase1 + k0);
    for (int cch = 0; cch < CPS; ++cch) {
        __syncthreads();
        *(bf16x8*)&As[arl * 40 + aqd * 8] = ra;
        *(bf16x8*)&Bs[bol0 * 40 + bqd * 8] = rb0;
        *(bf16x8*)&Bs[(64 + bol0) * 40 + bqd * 8] = rb1;
        __syncthreads();
        if (cch < CPS - 1) {
            int kn = k0 + (cch + 1) * 32;
            ra  = *(const bf16x8*)(abase + kn);
            rb0 = *(const bf16x8*)(bbase0 + kn);
            rb1 = *(const bf16x8*)(bbase1 + kn);
        }
        bf16x8 a[2], bb[4];
        #pragma unroll
        for (int rt = 0; rt < 2; ++rt)
            a[rt] = *(const bf16x8*)&As[(wr * 32 + rt * 16 + m16) * 40 + q * 8];
        #pragma unroll
        for (int ot = 0; ot < 4; ++ot)
            bb[ot] = *(const bf16x8*)&Bs[(wo * 64 + ot * 16 + m16) * 40 + q * 8];
        #pragma unroll
        for (int rt = 0; rt < 2; ++rt)
            #pragma unroll
            for (int ot = 0; ot < 4; ++ot)
                acc[rt][ot] = __builtin_amdgcn_mfma_f32_16x16x32_bf16(a[rt], bb[ot], acc[rt][ot], 0, 0, 0);
    }
    #pragma unroll
    for (int rt = 0; rt < 2; ++rt)
        #pragma unroll
        for (int ot = 0; ot < 4; ++ot) {
            int oc = ob * 128 + wo * 64 + ot * 16 + m16;
            #pragma unroll
            for (int rg = 0; rg < 4; ++rg) {
                int roi = rb * 64 + wr * 32 + rt * 16 + q * 4 + rg;
                Gpart[((long long)split * NROI + roi) * 256 + oc] = acc[rt][ot][rg];
            }
        }
}

__global__ __launch_bounds__(256) void reduce_G_kernel(
    const float* __restrict__ Gpart, float* __restrict__ G)
{
    int idx = blockIdx.x * 256 + threadIdx.x;
    float s = 0.f;
    #pragma unroll
    for (int sp = 0; sp < SPLITS; ++sp) s += Gpart[(long long)sp * NROI * 256 + idx];
    G[idx] = s;
}

// ---------------------------------------------------------------------------
// Fused tail: pair geometry + build_X + fc6 + fc7 + cls. Block = 64 pairs.
#define PHS 272
__global__ __launch_bounds__(256) void pair_head(
    const float* __restrict__ G, const float* __restrict__ d1,
    const float* __restrict__ d2, const float* __restrict__ wsum4,
    const float* __restrict__ hb,
    const u16* __restrict__ w6, const float* __restrict__ b6,
    const u16* __restrict__ w7, const float* __restrict__ b7,
    const float* __restrict__ cw, const float* __restrict__ cb,
    float* __restrict__ scores, float* __restrict__ labels,
    float* __restrict__ valid)
{
    __shared__ __align__(16) u16 bufA[64 * PHS];
    __shared__ __align__(16) u16 bufB[64 * PHS];
    __shared__ float Gs[2][256];
    __shared__ float ps[64][4];
    __shared__ float clw[256];

    const int tid = threadIdx.x;
    const int p0 = blockIdx.x * 64;
    const int r0 = p0 / MM;
    const int lane = tid & 63, w = tid >> 6;
    const int q = lane >> 4, m16 = lane & 15;

    clw[tid] = cw[tid];
    #pragma unroll
    for (int l = 0; l < 2; ++l) {
        int idx = tid + l * 256;
        int rr = idx >> 8, col = idx & 255;
        Gs[rr][col] = G[min(r0 + rr, NROI - 1) * 256 + col];
    }
    if (tid < 64) {
        int pair = p0 + tid;
        int b = pair / (MM * MM); int rem = pair % (MM * MM);
        int m1 = rem / MM, m2 = rem % MM;
        const float* rA = d1 + (long long)(b * MM + m1) * 10;
        const float* rB = d2 + (long long)(b * MM + m2) * 10;
        float v1 = rA[0], id1 = rA[1], cxa = rA[2], cya = rA[3], wa = rA[4], ha = rA[5];
        float v2 = rB[0], id2 = rB[1], cxb = rB[2], cyb = rB[3], wb = rB[4], hbv = rB[5];
        const float eps = 1e-6f;
        float ax1 = cxa - wa * 0.5f, ay1 = cya - ha * 0.5f;
        float ax2 = ax1 + wa,        ay2 = ay1 + ha;
        float bx1 = cxb - wb * 0.5f, by1 = cyb - hbv * 0.5f;
        float bx2 = bx1 + wb,        by2 = by1 + hbv;
        float ccx1 = (ax1 + ax2) * 0.5f, ccy1 = (ay1 + ay2) * 0.5f;
        float ww1 = fmaxf(ax2 - ax1, eps), hh1 = fmaxf(ay2 - ay1, eps);
        float ccx2 = (bx1 + bx2) * 0.5f, ccy2 = (by1 + by2) * 0.5f;
        float ww2 = fmaxf(bx2 - bx1, eps), hh2 = fmaxf(by2 - by1, eps);
        ps[tid][0] = (ccx2 - ccx1) / ww1;
        ps[tid][1] = (ccy2 - ccy1) / hh1;
        ps[tid][2] = logf(ww2 / ww1);
        ps[tid][3] = logf(hh2 / hh1);
        labels[pair] = (id1 == id2) ? 1.f : 0.f;
        valid[pair]  = (v1 != -1.f && v2 != -1.f) ? 1.f : 0.f;
    }
    __syncthreads();

    #pragma unroll
    for (int it = 0; it < 16; ++it) {
        int idx = tid + it * 256;            // 4096 = 64 px * 64 oc4
        int px = idx >> 6, o4 = (idx & 63) * 4;
        int rl = (p0 + px) / MM - r0;
        f32x4 g = *(const f32x4*)&Gs[rl][o4];
        f32x4 hv = *(const f32x4*)&hb[o4];
        f32x4 p4 = *(const f32x4*)&ps[px][0];
        u16x4 pk;
        #pragma unroll
        for (int j = 0; j < 4; ++j) {
            f32x4 w4 = *(const f32x4*)&wsum4[(o4 + j) * 4];
            float v = g[j] + hv[j] + p4[0] * w4[0] + p4[1] * w4[1] + p4[2] * w4[2] + p4[3] * w4[3];
            pk[j] = f2bf(v);
        }
        *(u16x4*)&bufA[px * PHS + o4] = pk;
    }
    __syncthreads();

    #pragma unroll
    for (int layer = 0; layer < 2; ++layer) {
        const u16* wgt = layer ? w7 : w6;
        const float* bs = layer ? b7 : b6;
        const u16* src = layer ? bufB : bufA;
        u16* dst = layer ? bufA : bufB;
        f32x4 acc[4][4];
        #pragma unroll
        for (int i = 0; i < 4; ++i)
            #pragma unroll
            for (int j = 0; j < 4; ++j) acc[i][j] = (f32x4){0.f, 0.f, 0.f, 0.f};
        #pragma unroll
        for (int kc = 0; kc < 8; ++kc) {
            bf16x8 a[4], bb[4];
            #pragma unroll
            for (int i = 0; i < 4; ++i)
                a[i] = *(const bf16x8*)&wgt[(w * 64 + i * 16 + m16) * 256 + kc * 32 + q * 8];
            #pragma unroll
            for (int pt = 0; pt < 4; ++pt)
                bb[pt] = *(const bf16x8*)&src[(pt * 16 + m16) * PHS + kc * 32 + q * 8];
            #pragma unroll
            for (int i = 0; i < 4; ++i)
                #pragma unroll
                for (int pt = 0; pt < 4; ++pt)
                    acc[i][pt] = __builtin_amdgcn_mfma_f32_16x16x32_bf16(a[i], bb[pt], acc[i][pt], 0, 0, 0);
        }
        #pragma unroll
        for (int i = 0; i < 4; ++i) {
            int oc4 = w * 64 + i * 16 + q * 4;
            f32x4 bv = *(const f32x4*)(bs + oc4);
            #pragma unroll
            for (int pt = 0; pt < 4; ++pt) {
                int px = pt * 16 + m16;
                f32x4 dd = acc[i][pt];
                u16x4 pk;
                #pragma unroll
                for (int rg = 0; rg < 4; ++rg)
                    pk[rg] = f2bf(fmaxf(dd[rg] + bv[rg], 0.f));
                *(u16x4*)&dst[px * PHS + oc4] = pk;
            }
        }
        __syncthreads();
    }

    {
        int px = tid >> 2, qq = tid & 3;
        float acc = 0.f;
        #pragma unroll
        for (int k8 = 0; k8 < 8; ++k8) {
            bf16x8 hv = *(const bf16x8*)&bufA[px * PHS + qq * 64 + k8 * 8];
            #pragma unroll
            for (int e = 0; e < 8; ++e)
                acc += b2f((u16)hv[e]) * clw[qq * 64 + k8 * 8 + e];
        }
        acc += __shfl_xor(acc, 1, 64);
        acc += __shfl_xor(acc, 2, 64);
        if (qq == 0) scores[p0 + px] = acc + cb[0];
    }
}

// ---------------------------------------------------------------------------
extern "C" void kernel_launch(void* const* d_in, const int* in_sizes, int n_in,
                              void* d_out, int out_size, void* d_ws, size_t ws_size,
                              hipStream_t stream) {
    const float* corr   = (const float*)d_in[0];
    const float* det1   = (const float*)d_in[2];
    const float* det2   = (const float*)d_in[3];
    const float* c1w    = (const float*)d_in[4];
    const float* c1b    = (const float*)d_in[5];
    const float* c2w    = (const float*)d_in[6];
    const float* c2b    = (const float*)d_in[7];
    const float* c3w    = (const float*)d_in[8];
    const float* c3b    = (const float*)d_in[9];
    const float* hw     = (const float*)d_in[10];
    const float* hbias  = (const float*)d_in[11];
    const float* f6w    = (const float*)d_in[12];
    const float* f6b    = (const float*)d_in[13];
    const float* f7w    = (const float*)d_in[14];
    const float* f7b    = (const float*)d_in[15];
    const float* clsw   = (const float*)d_in[16];
    const float* clsb   = (const float*)d_in[17];
    float* out = (float*)d_out;

    char* base = (char*)d_ws;
    auto alloc = [&](size_t bytes) { char* p = base; base += (bytes + 255) & ~(size_t)255; return p; };

    const size_t ACTP_BYTES = (size_t)NB * 98 * 98 * 256 * 2;
    u16*   act1p = (u16*)  alloc(ACTP_BYTES);
    u16*   act2p = (u16*)  alloc(ACTP_BYTES);
    u16*   rel   = (u16*)  alloc((size_t)NB * PIX * 128 * 2);
    u16*   wt1f  = (u16*)  alloc((size_t)11 * 16 * 512 * 2);
    u16*   wt2f  = (u16*)  alloc((size_t)2 * 16 * WSTAGE * 2);   // [ocb2][icb16][WSTAGE]
    u16*   wt3f  = (u16*)  alloc((size_t)16 * WSTAGE * 2);       // [icb16][WSTAGE]
    u16*   wtHt  = (u16*)  alloc((size_t)256 * KRF * 2);
    u16*   w6c   = (u16*)  alloc(256 * 256 * 2);
    u16*   w7c   = (u16*)  alloc(256 * 256 * 2);
    float* wsum4 = (float*)alloc(256 * 4 * 4);
    u16*   rf    = (u16*)  alloc((size_t)NROI * KRF * 2);
    float* Gpart = (float*)alloc((size_t)SPLITS * NROI * 256 * 4);
    float* G     = (float*)alloc(NROI * 256 * 4);

    float* scores_out = out;
    float* labels_out = out + NPAIR;
    float* valid_out  = out + 2 * NPAIR;

    zero_halo<<<388, 256, 0, stream>>>(act1p, act2p);
    prep_all<<<11940, 256, 0, stream>>>(c1w, c2w, c3w, hw, f6w, f7w,
                                        wt1f, wt2f, wt3f, wtHt, w6c, w7c, wsum4);
    conv1_mfma<<<dim3(144, NB), 512, 0, stream>>>(corr, wt1f, c1b, act1p);
    conv3x3_tp<256, 4, true><<<dim3(72, 2, NB), 256, 0, stream>>>(act1p, wt2f, c2b, act2p);
    conv3x3_tp<128, 2, false><<<dim3(144, 1, NB), 256, 0, stream>>>(act2p, wt3f, c3b, rel);
    roi_align_cl<<<NROI, 256, 0, stream>>>(rel, det1, rf);
    head_gemm_mfma<<<dim3(6, SPLITS), 256, 0, stream>>>(rf, wtHt, Gpart);
    reduce_G_kernel<<<NROI, 256, 0, stream>>>(Gpart, G);
    pair_head<<<144, 256, 0, stream>>>(G, det1, det2, wsum4, hbias,
                                       w6c, f6b, w7c, f7b, clsw, clsb,
                                       scores_out, labels_out, valid_out);
}

// Round 6
// 289.277 us; speedup vs baseline: 1.4188x; 1.1044x over previous
//
#include <hip/hip_runtime.h>
#include <hip/hip_bf16.h>

#define NB    4
#define HH    96
#define WW    96
#define PIX   9216
#define C0    324
#define MM    48
#define NROI  192
#define NPAIR 9216
#define KHEAD 6468
#define KRF   6272
#define SPLITS 28
#define CPS    7     // 28*7*32 = 6272

// conv2/3 weight stage: 9 taps x 4 octiles x 64 lanes x 8 = 18432 elems per (ocb,icb)
#define CWSTG 18432

typedef unsigned short u16;
typedef __attribute__((ext_vector_type(8))) short bf16x8;
typedef __attribute__((ext_vector_type(4))) float f32x4;
typedef __attribute__((ext_vector_type(16))) float f32x16;
typedef __attribute__((ext_vector_type(4))) unsigned short u16x4;
typedef __attribute__((ext_vector_type(4))) int i32x4;

__device__ __forceinline__ u16 f2bf(float f) {
    __hip_bfloat16 h = __float2bfloat16(f);
    union { __hip_bfloat16 h; u16 u; } c; c.h = h; return c.u;
}
__device__ __forceinline__ float b2f(u16 u) {
    union { unsigned int i; float f; } c; c.i = ((unsigned int)u) << 16; return c.f;
}

// ---------------------------------------------------------------------------
// Zero only the halo ring of act1p/act2p
__global__ __launch_bounds__(256) void zero_halo(u16* __restrict__ a1, u16* __restrict__ a2)
{
    int idx = blockIdx.x * 256 + threadIdx.x;   // 99328 total
    int c8 = idx & 31;
    int t = idx >> 5;
    int h = t % 388, img = t / 388;             // img 0..7
    u16* base = (img & 4) ? a2 : a1;
    int b = img & 3;
    int y, x;
    if (h < 98)       { y = 0;  x = h; }
    else if (h < 196) { y = 97; x = h - 98; }
    else { int r = (h - 196) >> 1; x = ((h - 196) & 1) * 97; y = 1 + r; }
    long long off = (((long long)(b * 98 + y)) * 98 + x) * 256 + c8 * 8;
    i32x4 z = {0, 0, 0, 0};
    *(i32x4*)(base + off) = z;
}

// ---------------------------------------------------------------------------
// Merged prep. Block ranges:
// [0,352) wt1 | [352,2656) wt2 | [2656,3808) wt3 | [3808,10080) wtH
// [10080,10336) w6 | [10336,10592) w7 | [10592,10596) wsum
// wt1f: [ks22][ot8][lane64][j8]  (oc = ot*32+(lane&31), k = ks*16+8*(lane>>5)+j)
// wt2f: [ocb2][icb16][tap9][ot4][lane64][j8]
// wt3f: [icb16][tap9][ot4][lane64][j8]
__global__ __launch_bounds__(256) void prep_all(
    const float* __restrict__ c1w, const float* __restrict__ c2w,
    const float* __restrict__ c3w, const float* __restrict__ hw,
    const float* __restrict__ f6w, const float* __restrict__ f7w,
    u16* __restrict__ wt1f, u16* __restrict__ wt2f, u16* __restrict__ wt3f,
    u16* __restrict__ wtHt, u16* __restrict__ w6c, u16* __restrict__ w7c,
    float* __restrict__ wsum4)
{
    int blk = blockIdx.x, tid = threadIdx.x;
    if (blk < 352) {
        int idx = blk * 256 + tid;            // 22*8*64*8 = 90112
        if (idx >= 90112) return;
        int j = idx & 7, lane = (idx >> 3) & 63, ot = (idx >> 9) & 7, ks = idx >> 12;
        int oc = ot * 32 + (lane & 31);
        int k = ks * 16 + (lane >> 5) * 8 + j;
        wt1f[idx] = f2bf((k < C0) ? c1w[oc * C0 + k] : 0.f);
    } else if (blk < 2656) {
        int idx = (blk - 352) * 256 + tid;    // 589824
        int j = idx & 7, lane = (idx >> 3) & 63, ot = (idx >> 9) & 3;
        int t = idx >> 11;
        int tap = t % 9; t /= 9;
        int icb = t & 15, ocb = t >> 4;
        int oc = ocb * 128 + ot * 32 + (lane & 31);
        int ic = icb * 16 + (lane >> 5) * 8 + j;
        wt2f[idx] = f2bf(c2w[(oc * 256 + ic) * 9 + tap]);
    } else if (blk < 3808) {
        int idx = (blk - 2656) * 256 + tid;   // 294912
        int j = idx & 7, lane = (idx >> 3) & 63, ot = (idx >> 9) & 3;
        int t = idx >> 11;
        int tap = t % 9; int icb = t / 9;     // 0..15
        int oc = ot * 32 + (lane & 31);
        int ic = icb * 16 + (lane >> 5) * 8 + j;
        wt3f[idx] = f2bf(c3w[(oc * 256 + ic) * 9 + tap]);
    } else if (blk < 10080) {
        int idx = (blk - 3808) * 256 + tid;   // 256*6272
        int oc = idx / KRF, r = idx % KRF;
        int s = r >> 7, c = r & 127;
        wtHt[idx] = f2bf(hw[oc * KHEAD + c * 49 + s]);
    } else if (blk < 10336) {
        int idx = (blk - 10080) * 256 + tid;
        w6c[idx] = f2bf(f6w[idx]);
    } else if (blk < 10592) {
        int idx = (blk - 10336) * 256 + tid;
        w7c[idx] = f2bf(f7w[idx]);
    } else {
        int idx = (blk - 10592) * 256 + tid;  // 1024
        if (idx >= 1024) return;
        int oc = idx >> 2, j = idx & 3;
        const float* p = hw + (long long)oc * KHEAD + (128 + j) * 49;
        float s = 0.f;
        #pragma unroll
        for (int t = 0; t < 49; ++t) s += p[t];
        wsum4[idx] = s;
    }
}

// ---------------------------------------------------------------------------
// conv1 (1x1, K=324->352) fused fp32 transpose + 32x32x16 MFMA.
// Block 256 thr = 4 waves (2 ocw x 2 pxw). Tile 256 oc x 64 px. Grid (144, 4).
__global__ __launch_bounds__(256) void conv1_v2(
    const float* __restrict__ corr, const u16* __restrict__ wf,
    const float* __restrict__ bias, u16* __restrict__ outp)
{
    __shared__ __align__(16) u16 Ws1[8192];   // [ks2][otg8][lane64][8] per 32k stage
    __shared__ __align__(16) u16 Bs[64 * 40]; // [px64][k32 pad40]
    const int tid = threadIdx.x;
    const int b = blockIdx.y;
    const int p0 = blockIdx.x * 64;
    const int lane = tid & 63, wid = tid >> 6;
    const int n = lane & 31, half = lane >> 5;
    const int wocw = wid & 1, wpx = wid >> 1;
    const int kr = tid >> 3, pxg = tid & 7;   // kr 0..31, pxg 0..7 (8 px each)

    f32x16 acc[4];
    #pragma unroll
    for (int i = 0; i < 4; ++i)
        #pragma unroll
        for (int e = 0; e < 16; ++e) acc[i][e] = 0.f;

    float4 s0 = {0,0,0,0}, s1 = {0,0,0,0};
    if (kr < C0) {
        const float* src = &corr[((long long)(b * C0 + kr)) * PIX + p0 + pxg * 8];
        s0 = *(const float4*)src; s1 = *(const float4*)(src + 4);
    }
    bf16x8 wr[4];
    #pragma unroll
    for (int i = 0; i < 4; ++i) wr[i] = *(const bf16x8*)(wf + (i * 256 + tid) * 8);

    for (int kc = 0; kc < 11; ++kc) {
        __syncthreads();
        Bs[(pxg * 8 + 0) * 40 + kr] = f2bf(s0.x);
        Bs[(pxg * 8 + 1) * 40 + kr] = f2bf(s0.y);
        Bs[(pxg * 8 + 2) * 40 + kr] = f2bf(s0.z);
        Bs[(pxg * 8 + 3) * 40 + kr] = f2bf(s0.w);
        Bs[(pxg * 8 + 4) * 40 + kr] = f2bf(s1.x);
        Bs[(pxg * 8 + 5) * 40 + kr] = f2bf(s1.y);
        Bs[(pxg * 8 + 6) * 40 + kr] = f2bf(s1.z);
        Bs[(pxg * 8 + 7) * 40 + kr] = f2bf(s1.w);
        #pragma unroll
        for (int i = 0; i < 4; ++i) *(bf16x8*)&Ws1[(i * 256 + tid) * 8] = wr[i];
        __syncthreads();
        if (kc < 10) {
            int k = (kc + 1) * 32 + kr;
            if (k < C0) {
                const float* src = &corr[((long long)(b * C0 + k)) * PIX + p0 + pxg * 8];
                s0 = *(const float4*)src; s1 = *(const float4*)(src + 4);
            } else { s0 = (float4){0,0,0,0}; s1 = (float4){0,0,0,0}; }
            const u16* wn = wf + (kc + 1) * 8192;
            #pragma unroll
            for (int i = 0; i < 4; ++i) wr[i] = *(const bf16x8*)(wn + (i * 256 + tid) * 8);
        }
        #pragma unroll
        for (int ks = 0; ks < 2; ++ks) {
            bf16x8 bb = *(const bf16x8*)&Bs[(wpx * 32 + n) * 40 + ks * 16 + half * 8];
            #pragma unroll
            for (int ot = 0; ot < 4; ++ot) {
                bf16x8 a = *(const bf16x8*)&Ws1[((ks * 8 + wocw * 4 + ot) * 64 + lane) * 8];
                acc[ot] = __builtin_amdgcn_mfma_f32_32x32x16_bf16(a, bb, acc[ot], 0, 0, 0);
            }
        }
    }
    const int px = p0 + wpx * 32 + n;
    const int y = px / 96, x = px % 96;
    const long long obase = (((long long)(b * 98 + y + 1)) * 98 + x + 1) * 256;
    #pragma unroll
    for (int ot = 0; ot < 4; ++ot) {
        int ocb = wocw * 128 + ot * 32;
        f32x16 d = acc[ot];
        #pragma unroll
        for (int r2 = 0; r2 < 4; ++r2) {
            int oc4 = ocb + r2 * 8 + half * 4;
            f32x4 bv = *(const f32x4*)(bias + oc4);
            u16x4 pk;
            #pragma unroll
            for (int g = 0; g < 4; ++g) pk[g] = f2bf(fmaxf(d[r2 * 4 + g] + bv[g], 0.f));
            *(u16x4*)(outp + obase + oc4) = pk;
        }
    }
}

// ---------------------------------------------------------------------------
// conv3x3 via 32x32x16 MFMA. Block: 128 oc x (4 rows x 32 cols), 4 waves
// (2 ocw x 2 roww), wave = 64 oc x (2 rows x 32 cols). 16-ic stages, K=16 =
// 1 tap x 16 ic (no padding). B-frags register-cached (12 distinct per stage).
// Frag-ready weights in LDS; halo [6][34][ic16 pad24].
template<int COUT, bool PADOUT>
__global__ __launch_bounds__(256, 2) void conv3x3_v2(
    const u16* __restrict__ inp, const u16* __restrict__ wf,
    const float* __restrict__ bias, u16* __restrict__ outp)
{
    __shared__ __align__(16) u16 Ws[CWSTG];      // [tap9][ot4][lane64][8]
    __shared__ __align__(16) u16 Hs[204 * 24];   // [row6][col34][ic16 pad24]
    const int tid = threadIdx.x;
    const int b = blockIdx.z;
    const int x0 = (blockIdx.x % 3) * 32, y0 = (blockIdx.x / 3) * 4;
    const int lane = tid & 63, wid = tid >> 6;
    const int n = lane & 31, half = lane >> 5;
    const int woc = wid & 1, wpx = wid >> 1;

    const u16* wsrc = wf + (size_t)blockIdx.y * 16 * CWSTG;
    const bool hstager = tid < 204;
    const int hrow = tid / 34, hcol = tid % 34;
    const u16* hsrc = inp + (((size_t)(b * 98 + y0 + hrow)) * 98 + x0 + hcol) * 256;

    f32x16 acc[2][2];
    #pragma unroll
    for (int i = 0; i < 2; ++i)
        #pragma unroll
        for (int r = 0; r < 2; ++r)
            #pragma unroll
            for (int e = 0; e < 16; ++e) acc[i][r][e] = 0.f;

    bf16x8 wreg[9];
    bf16x8 h0, h1;
    #pragma unroll
    for (int it = 0; it < 9; ++it)
        wreg[it] = *(const bf16x8*)(wsrc + (it * 256 + tid) * 8);
    if (hstager) { h0 = *(const bf16x8*)hsrc; h1 = *(const bf16x8*)(hsrc + 8); }

    for (int icb = 0; icb < 16; ++icb) {
        __syncthreads();
        #pragma unroll
        for (int it = 0; it < 9; ++it)
            *(bf16x8*)&Ws[(it * 256 + tid) * 8] = wreg[it];
        if (hstager) {
            *(bf16x8*)&Hs[tid * 24]     = h0;
            *(bf16x8*)&Hs[tid * 24 + 8] = h1;
        }
        __syncthreads();
        if (icb < 15) {
            const u16* wn = wsrc + (size_t)(icb + 1) * CWSTG;
            #pragma unroll
            for (int it = 0; it < 9; ++it)
                wreg[it] = *(const bf16x8*)(wn + (it * 256 + tid) * 8);
            if (hstager) {
                const u16* hn = hsrc + (icb + 1) * 16;
                h0 = *(const bf16x8*)hn; h1 = *(const bf16x8*)(hn + 8);
            }
        }
        // cache the 12 distinct B fragments (4 halo rows x 3 dx)
        bf16x8 bfr[4][3];
        #pragma unroll
        for (int rr = 0; rr < 4; ++rr)
            #pragma unroll
            for (int dx = 0; dx < 3; ++dx)
                bfr[rr][dx] = *(const bf16x8*)&Hs[((wpx * 2 + rr) * 34 + dx + n) * 24 + half * 8];
        #pragma unroll
        for (int tap = 0; tap < 9; ++tap) {
            const int dy = tap / 3, dx = tap % 3;
            bf16x8 a0 = *(const bf16x8*)&Ws[((tap * 4 + woc * 2 + 0) * 64 + lane) * 8];
            bf16x8 a1 = *(const bf16x8*)&Ws[((tap * 4 + woc * 2 + 1) * 64 + lane) * 8];
            #pragma unroll
            for (int r = 0; r < 2; ++r) {
                acc[0][r] = __builtin_amdgcn_mfma_f32_32x32x16_bf16(a0, bfr[r + dy][dx], acc[0][r], 0, 0, 0);
                acc[1][r] = __builtin_amdgcn_mfma_f32_32x32x16_bf16(a1, bfr[r + dy][dx], acc[1][r], 0, 0, 0);
            }
        }
    }
    #pragma unroll
    for (int ot = 0; ot < 2; ++ot) {
        int ocb = blockIdx.y * 128 + woc * 64 + ot * 32;
        #pragma unroll
        for (int r = 0; r < 2; ++r) {
            int y = y0 + wpx * 2 + r;
            int x = x0 + n;
            f32x16 d = acc[ot][r];
            long long obase;
            if (PADOUT) obase = (((long long)(b * 98 + y + 1)) * 98 + x + 1) * COUT;
            else        obase = (((long long)(b * 96 + y)) * 96 + x) * COUT;
            #pragma unroll
            for (int r2 = 0; r2 < 4; ++r2) {
                int oc4 = ocb + r2 * 8 + half * 4;
                f32x4 bv = *(const f32x4*)(bias + oc4);
                u16x4 pk;
                #pragma unroll
                for (int g = 0; g < 4; ++g) pk[g] = f2bf(fmaxf(d[r2 * 4 + g] + bv[g], 0.f));
                *(u16x4*)(outp + obase + oc4) = pk;
            }
        }
    }
}

// ---------------------------------------------------------------------------
// ROI align: rel [4][96][96][128] bf16 -> rf [192][6272] bf16 (k' = s*128+c)
__global__ __launch_bounds__(256) void roi_align_cl(
    const u16* __restrict__ rel, const float* __restrict__ det1,
    u16* __restrict__ rf)
{
    const int roi = blockIdx.x, tid = threadIdx.x;
    const int c = tid & 127, sb = tid >> 7;
    const int b = roi / MM, m = roi % MM;
    const float* d = det1 + (long long)(b * MM + m) * 10;
    float cx = d[2], cy = d[3], w = d[4], h = d[5];
    float x1f = cx - w * 0.5f, y1f = cy - h * 0.5f;
    float x1 = x1f * 0.125f, y1 = y1f * 0.125f;
    float x2 = (x1f + w) * 0.125f, y2 = (y1f + h) * 0.125f;
    float bh = (y2 - y1) * (1.f / 7.f), bw = (x2 - x1) * (1.f / 7.f);
    const u16* fb = rel + (long long)b * PIX * 128 + c;
    for (int s = sb; s < 49; s += 2) {
        int i = s / 7, j = s % 7;
        float sum = 0.f;
        #pragma unroll
        for (int di = 0; di < 2; ++di) {
            float y = y1 + ((float)(2 * i + di) + 0.5f) * 0.5f * bh;
            y = fminf(fmaxf(y, 0.f), 95.f);
            int yy0 = (int)floorf(y);
            int yy1 = min(yy0 + 1, 95);
            float wy = y - (float)yy0;
            #pragma unroll
            for (int dj = 0; dj < 2; ++dj) {
                float x = x1 + ((float)(2 * j + dj) + 0.5f) * 0.5f * bw;
                x = fminf(fmaxf(x, 0.f), 95.f);
                int xx0 = (int)floorf(x);
                int xx1 = min(xx0 + 1, 95);
                float wx = x - (float)xx0;
                float f00 = b2f(fb[((long long)yy0 * 96 + xx0) * 128]);
                float f01 = b2f(fb[((long long)yy0 * 96 + xx1) * 128]);
                float f10 = b2f(fb[((long long)yy1 * 96 + xx0) * 128]);
                float f11 = b2f(fb[((long long)yy1 * 96 + xx1) * 128]);
                sum += f00 * (1.f - wy) * (1.f - wx) + f01 * (1.f - wy) * wx
                     + f10 * wy * (1.f - wx) + f11 * wy * wx;
            }
        }
        rf[(long long)roi * KRF + s * 128 + c] = f2bf(sum * 0.25f);
    }
}

// ---------------------------------------------------------------------------
// Head GEMM split-K (28 splits x 7 chunks). Block 64 rois x 128 oc. Grid (6,28).
__global__ __launch_bounds__(256) void head_gemm_mfma(
    const u16* __restrict__ rf, const u16* __restrict__ wtHt,
    float* __restrict__ Gpart)
{
    __shared__ __align__(16) u16 As[64 * 40];
    __shared__ __align__(16) u16 Bs[128 * 40];
    const int tid = threadIdx.x;
    const int rb = blockIdx.x >> 1, ob = blockIdx.x & 1;
    const int split = blockIdx.y;
    const int lane = tid & 63, wid = tid >> 6;
    const int q = lane >> 4, m16 = lane & 15;
    const int wr = wid & 1, wo = wid >> 1;

    const int arl = tid >> 2, aqd = tid & 3;
    const u16* abase = rf + (long long)(rb * 64 + arl) * KRF + aqd * 8;
    const int bol0 = tid >> 2, bqd = tid & 3;
    const u16* bbase0 = wtHt + (long long)(ob * 128 + bol0) * KRF + bqd * 8;
    const u16* bbase1 = bbase0 + 64LL * KRF;

    f32x4 acc[2][4];
    #pragma unroll
    for (int i = 0; i < 2; ++i)
        #pragma unroll
        for (int j = 0; j < 4; ++j) acc[i][j] = (f32x4){0.f, 0.f, 0.f, 0.f};

    int k0 = split * CPS * 32;
    bf16x8 ra = *(const bf16x8*)(abase + k0);
    bf16x8 rb0 = *(const bf16x8*)(bbase0 + k0);
    bf16x8 rb1 = *(const bf16x8*)(bbase1 + k0);
    for (int cch = 0; cch < CPS; ++cch) {
        __syncthreads();
        *(bf16x8*)&As[arl * 40 + aqd * 8] = ra;
        *(bf16x8*)&Bs[bol0 * 40 + bqd * 8] = rb0;
        *(bf16x8*)&Bs[(64 + bol0) * 40 + bqd * 8] = rb1;
        __syncthreads();
        if (cch < CPS - 1) {
            int kn = k0 + (cch + 1) * 32;
            ra  = *(const bf16x8*)(abase + kn);
            rb0 = *(const bf16x8*)(bbase0 + kn);
            rb1 = *(const bf16x8*)(bbase1 + kn);
        }
        bf16x8 a[2], bb[4];
        #pragma unroll
        for (int rt = 0; rt < 2; ++rt)
            a[rt] = *(const bf16x8*)&As[(wr * 32 + rt * 16 + m16) * 40 + q * 8];
        #pragma unroll
        for (int ot = 0; ot < 4; ++ot)
            bb[ot] = *(const bf16x8*)&Bs[(wo * 64 + ot * 16 + m16) * 40 + q * 8];
        #pragma unroll
        for (int rt = 0; rt < 2; ++rt)
            #pragma unroll
            for (int ot = 0; ot < 4; ++ot)
                acc[rt][ot] = __builtin_amdgcn_mfma_f32_16x16x32_bf16(a[rt], bb[ot], acc[rt][ot], 0, 0, 0);
    }
    #pragma unroll
    for (int rt = 0; rt < 2; ++rt)
        #pragma unroll
        for (int ot = 0; ot < 4; ++ot) {
            int oc = ob * 128 + wo * 64 + ot * 16 + m16;
            #pragma unroll
            for (int rg = 0; rg < 4; ++rg) {
                int roi = rb * 64 + wr * 32 + rt * 16 + q * 4 + rg;
                Gpart[((long long)split * NROI + roi) * 256 + oc] = acc[rt][ot][rg];
            }
        }
}

__global__ __launch_bounds__(256) void reduce_G_kernel(
    const float* __restrict__ Gpart, float* __restrict__ G)
{
    int idx = blockIdx.x * 256 + threadIdx.x;
    float s = 0.f;
    #pragma unroll
    for (int sp = 0; sp < SPLITS; ++sp) s += Gpart[(long long)sp * NROI * 256 + idx];
    G[idx] = s;
}

// ---------------------------------------------------------------------------
// Fused tail: pair geometry + build_X + fc6 + fc7 + cls. Block = 64 pairs.
#define PHS 272
__global__ __launch_bounds__(256) void pair_head(
    const float* __restrict__ G, const float* __restrict__ d1,
    const float* __restrict__ d2, const float* __restrict__ wsum4,
    const float* __restrict__ hb,
    const u16* __restrict__ w6, const float* __restrict__ b6,
    const u16* __restrict__ w7, const float* __restrict__ b7,
    const float* __restrict__ cw, const float* __restrict__ cb,
    float* __restrict__ scores, float* __restrict__ labels,
    float* __restrict__ valid)
{
    __shared__ __align__(16) u16 bufA[64 * PHS];
    __shared__ __align__(16) u16 bufB[64 * PHS];
    __shared__ float Gs[2][256];
    __shared__ float ps[64][4];
    __shared__ float clw[256];

    const int tid = threadIdx.x;
    const int p0 = blockIdx.x * 64;
    const int r0 = p0 / MM;
    const int lane = tid & 63, w = tid >> 6;
    const int q = lane >> 4, m16 = lane & 15;

    clw[tid] = cw[tid];
    #pragma unroll
    for (int l = 0; l < 2; ++l) {
        int idx = tid + l * 256;
        int rr = idx >> 8, col = idx & 255;
        Gs[rr][col] = G[min(r0 + rr, NROI - 1) * 256 + col];
    }
    if (tid < 64) {
        int pair = p0 + tid;
        int b = pair / (MM * MM); int rem = pair % (MM * MM);
        int m1 = rem / MM, m2 = rem % MM;
        const float* rA = d1 + (long long)(b * MM + m1) * 10;
        const float* rB = d2 + (long long)(b * MM + m2) * 10;
        float v1 = rA[0], id1 = rA[1], cxa = rA[2], cya = rA[3], wa = rA[4], ha = rA[5];
        float v2 = rB[0], id2 = rB[1], cxb = rB[2], cyb = rB[3], wb = rB[4], hbv = rB[5];
        const float eps = 1e-6f;
        float ax1 = cxa - wa * 0.5f, ay1 = cya - ha * 0.5f;
        float ax2 = ax1 + wa,        ay2 = ay1 + ha;
        float bx1 = cxb - wb * 0.5f, by1 = cyb - hbv * 0.5f;
        float bx2 = bx1 + wb,        by2 = by1 + hbv;
        float ccx1 = (ax1 + ax2) * 0.5f, ccy1 = (ay1 + ay2) * 0.5f;
        float ww1 = fmaxf(ax2 - ax1, eps), hh1 = fmaxf(ay2 - ay1, eps);
        float ccx2 = (bx1 + bx2) * 0.5f, ccy2 = (by1 + by2) * 0.5f;
        float ww2 = fmaxf(bx2 - bx1, eps), hh2 = fmaxf(by2 - by1, eps);
        ps[tid][0] = (ccx2 - ccx1) / ww1;
        ps[tid][1] = (ccy2 - ccy1) / hh1;
        ps[tid][2] = logf(ww2 / ww1);
        ps[tid][3] = logf(hh2 / hh1);
        labels[pair] = (id1 == id2) ? 1.f : 0.f;
        valid[pair]  = (v1 != -1.f && v2 != -1.f) ? 1.f : 0.f;
    }
    __syncthreads();

    #pragma unroll
    for (int it = 0; it < 16; ++it) {
        int idx = tid + it * 256;            // 4096 = 64 px * 64 oc4
        int px = idx >> 6, o4 = (idx & 63) * 4;
        int rl = (p0 + px) / MM - r0;
        f32x4 g = *(const f32x4*)&Gs[rl][o4];
        f32x4 hv = *(const f32x4*)&hb[o4];
        f32x4 p4 = *(const f32x4*)&ps[px][0];
        u16x4 pk;
        #pragma unroll
        for (int j = 0; j < 4; ++j) {
            f32x4 w4 = *(const f32x4*)&wsum4[(o4 + j) * 4];
            float v = g[j] + hv[j] + p4[0] * w4[0] + p4[1] * w4[1] + p4[2] * w4[2] + p4[3] * w4[3];
            pk[j] = f2bf(v);
        }
        *(u16x4*)&bufA[px * PHS + o4] = pk;
    }
    __syncthreads();

    #pragma unroll
    for (int layer = 0; layer < 2; ++layer) {
        const u16* wgt = layer ? w7 : w6;
        const float* bs = layer ? b7 : b6;
        const u16* src = layer ? bufB : bufA;
        u16* dst = layer ? bufA : bufB;
        f32x4 acc[4][4];
        #pragma unroll
        for (int i = 0; i < 4; ++i)
            #pragma unroll
            for (int j = 0; j < 4; ++j) acc[i][j] = (f32x4){0.f, 0.f, 0.f, 0.f};
        #pragma unroll
        for (int kc = 0; kc < 8; ++kc) {
            bf16x8 a[4], bb[4];
            #pragma unroll
            for (int i = 0; i < 4; ++i)
                a[i] = *(const bf16x8*)&wgt[(w * 64 + i * 16 + m16) * 256 + kc * 32 + q * 8];
            #pragma unroll
            for (int pt = 0; pt < 4; ++pt)
                bb[pt] = *(const bf16x8*)&src[(pt * 16 + m16) * PHS + kc * 32 + q * 8];
            #pragma unroll
            for (int i = 0; i < 4; ++i)
                #pragma unroll
                for (int pt = 0; pt < 4; ++pt)
                    acc[i][pt] = __builtin_amdgcn_mfma_f32_16x16x32_bf16(a[i], bb[pt], acc[i][pt], 0, 0, 0);
        }
        #pragma unroll
        for (int i = 0; i < 4; ++i) {
            int oc4 = w * 64 + i * 16 + q * 4;
            f32x4 bv = *(const f32x4*)(bs + oc4);
            #pragma unroll
            for (int pt = 0; pt < 4; ++pt) {
                int px = pt * 16 + m16;
                f32x4 dd = acc[i][pt];
                u16x4 pk;
                #pragma unroll
                for (int rg = 0; rg < 4; ++rg)
                    pk[rg] = f2bf(fmaxf(dd[rg] + bv[rg], 0.f));
                *(u16x4*)&dst[px * PHS + oc4] = pk;
            }
        }
        __syncthreads();
    }

    {
        int px = tid >> 2, qq = tid & 3;
        float acc = 0.f;
        #pragma unroll
        for (int k8 = 0; k8 < 8; ++k8) {
            bf16x8 hv = *(const bf16x8*)&bufA[px * PHS + qq * 64 + k8 * 8];
            #pragma unroll
            for (int e = 0; e < 8; ++e)
                acc += b2f((u16)hv[e]) * clw[qq * 64 + k8 * 8 + e];
        }
        acc += __shfl_xor(acc, 1, 64);
        acc += __shfl_xor(acc, 2, 64);
        if (qq == 0) scores[p0 + px] = acc + cb[0];
    }
}

// ---------------------------------------------------------------------------
extern "C" void kernel_launch(void* const* d_in, const int* in_sizes, int n_in,
                              void* d_out, int out_size, void* d_ws, size_t ws_size,
                              hipStream_t stream) {
    const float* corr   = (const float*)d_in[0];
    const float* det1   = (const float*)d_in[2];
    const float* det2   = (const float*)d_in[3];
    const float* c1w    = (const float*)d_in[4];
    const float* c1b    = (const float*)d_in[5];
    const float* c2w    = (const float*)d_in[6];
    const float* c2b    = (const float*)d_in[7];
    const float* c3w    = (const float*)d_in[8];
    const float* c3b    = (const float*)d_in[9];
    const float* hw     = (const float*)d_in[10];
    const float* hbias  = (const float*)d_in[11];
    const float* f6w    = (const float*)d_in[12];
    const float* f6b    = (const float*)d_in[13];
    const float* f7w    = (const float*)d_in[14];
    const float* f7b    = (const float*)d_in[15];
    const float* clsw   = (const float*)d_in[16];
    const float* clsb   = (const float*)d_in[17];
    float* out = (float*)d_out;

    char* base = (char*)d_ws;
    auto alloc = [&](size_t bytes) { char* p = base; base += (bytes + 255) & ~(size_t)255; return p; };

    const size_t ACTP_BYTES = (size_t)NB * 98 * 98 * 256 * 2;
    u16*   act1p = (u16*)  alloc(ACTP_BYTES);
    u16*   act2p = (u16*)  alloc(ACTP_BYTES);
    u16*   rel   = (u16*)  alloc((size_t)NB * PIX * 128 * 2);
    u16*   wt1f  = (u16*)  alloc((size_t)90112 * 2);             // [ks22][ot8][lane][8]
    u16*   wt2f  = (u16*)  alloc((size_t)2 * 16 * CWSTG * 2);    // [ocb2][icb16][CWSTG]
    u16*   wt3f  = (u16*)  alloc((size_t)16 * CWSTG * 2);        // [icb16][CWSTG]
    u16*   wtHt  = (u16*)  alloc((size_t)256 * KRF * 2);
    u16*   w6c   = (u16*)  alloc(256 * 256 * 2);
    u16*   w7c   = (u16*)  alloc(256 * 256 * 2);
    float* wsum4 = (float*)alloc(256 * 4 * 4);
    u16*   rf    = (u16*)  alloc((size_t)NROI * KRF * 2);
    float* Gpart = (float*)alloc((size_t)SPLITS * NROI * 256 * 4);
    float* G     = (float*)alloc(NROI * 256 * 4);

    float* scores_out = out;
    float* labels_out = out + NPAIR;
    float* valid_out  = out + 2 * NPAIR;

    zero_halo<<<388, 256, 0, stream>>>(act1p, act2p);
    prep_all<<<10596, 256, 0, stream>>>(c1w, c2w, c3w, hw, f6w, f7w,
                                        wt1f, wt2f, wt3f, wtHt, w6c, w7c, wsum4);
    conv1_v2<<<dim3(144, NB), 256, 0, stream>>>(corr, wt1f, c1b, act1p);
    conv3x3_v2<256, true><<<dim3(72, 2, NB), 256, 0, stream>>>(act1p, wt2f, c2b, act2p);
    conv3x3_v2<128, false><<<dim3(72, 1, NB), 256, 0, stream>>>(act2p, wt3f, c3b, rel);
    roi_align_cl<<<NROI, 256, 0, stream>>>(rel, det1, rf);
    head_gemm_mfma<<<dim3(6, SPLITS), 256, 0, stream>>>(rf, wtHt, Gpart);
    reduce_G_kernel<<<NROI, 256, 0, stream>>>(Gpart, G);
    pair_head<<<144, 256, 0, stream>>>(G, det1, det2, wsum4, hbias,
                                       w6c, f6b, w7c, f7b, clsw, clsb,
                                       scores_out, labels_out, valid_out);
}

// Round 7
// 282.304 us; speedup vs baseline: 1.4538x; 1.0247x over previous
//
#include <hip/hip_runtime.h>
#include <hip/hip_bf16.h>

#define NB    4
#define HH    96
#define WW    96
#define PIX   9216
#define C0    324
#define MM    48
#define NROI  192
#define NPAIR 9216
#define KHEAD 6468
#define KRF   6272
#define SPLITS 28
#define CPS    7     // 28*7*32 = 6272

// conv2/3 weight stage: 9 taps x 4 octiles x 64 lanes x 8 = 18432 elems per (ocb,icb)
#define CWSTG 18432

typedef unsigned short u16;
typedef __attribute__((ext_vector_type(8))) short bf16x8;
typedef __attribute__((ext_vector_type(4))) float f32x4;
typedef __attribute__((ext_vector_type(16))) float f32x16;
typedef __attribute__((ext_vector_type(4))) unsigned short u16x4;
typedef __attribute__((ext_vector_type(8))) unsigned short u16x8;
typedef __attribute__((ext_vector_type(4))) int i32x4;

__device__ __forceinline__ u16 f2bf(float f) {
    __hip_bfloat16 h = __float2bfloat16(f);
    union { __hip_bfloat16 h; u16 u; } c; c.h = h; return c.u;
}
__device__ __forceinline__ float b2f(u16 u) {
    union { unsigned int i; float f; } c; c.i = ((unsigned int)u) << 16; return c.f;
}

// ---------------------------------------------------------------------------
// Merged prep + halo-zero. All source reads are linear float4; all dest writes
// are coalesced 16B chunks. Block ranges:
// [0,8)    wt1   (block = 1 octile = 32 oc)
// [8,40)   wt2   (block = 8 oc)
// [40,56)  wt3   (block = 8 oc)
// [56,312) wtH   (block = 1 oc) + wsum4
// [312,328) w6 | [328,344) w7 | [344,732) zero halo
__global__ __launch_bounds__(256) void prep_v2(
    const float* __restrict__ c1w, const float* __restrict__ c2w,
    const float* __restrict__ c3w, const float* __restrict__ hw,
    const float* __restrict__ f6w, const float* __restrict__ f7w,
    u16* __restrict__ wt1f, u16* __restrict__ wt2f, u16* __restrict__ wt3f,
    u16* __restrict__ wtHt, u16* __restrict__ w6c, u16* __restrict__ w7c,
    float* __restrict__ wsum4, u16* __restrict__ a1, u16* __restrict__ a2)
{
    __shared__ u16 L[18432];
    const int blk = blockIdx.x, tid = threadIdx.x;

    if (blk < 8) {
        // conv1 weights: 32 oc x 324 k -> [ks22][ot8][lane64][j8]
        const int ot = blk;
        const float* src = c1w + (size_t)ot * 32 * C0;
        for (int it = 0; it < 11; ++it) {
            int i = tid + it * 256;
            if (i < 2592) {                    // 32*324/4
                float4 v = *(const float4*)(src + i * 4);
                int n = i / 81, k4 = (i % 81) * 4;
                L[n * 324 + k4 + 0] = f2bf(v.x);
                L[n * 324 + k4 + 1] = f2bf(v.y);
                L[n * 324 + k4 + 2] = f2bf(v.z);
                L[n * 324 + k4 + 3] = f2bf(v.w);
            }
        }
        __syncthreads();
        for (int it = 0; it < 6; ++it) {
            int v = tid + it * 256;
            if (v >= 1408) break;              // 22*64
            int ks = v >> 6, lane = v & 63;
            int n = lane & 31, half = lane >> 5;
            u16x8 pk;
            #pragma unroll
            for (int j = 0; j < 8; ++j) {
                int k = ks * 16 + half * 8 + j;
                pk[j] = (k < C0) ? L[n * 324 + k] : (u16)0;
            }
            *(u16x8*)&wt1f[((ks * 8 + ot) * 64 + lane) * 8] = pk;
        }
    } else if (blk < 56) {
        // conv2/conv3 weights: block = 8 oc. src rows 2304 fp32.
        const bool is2 = blk < 40;
        const int b8 = is2 ? (blk - 8) : (blk - 40);
        const int oc8 = b8 * 8;
        const int ocb = oc8 >> 7;              // 0..1 (conv2), 0 (conv3)
        const int ot = (oc8 >> 5) & 3;
        const int nb = oc8 & 31;
        const float* src = (is2 ? c2w : c3w) + (size_t)oc8 * 2304;
        u16* dst = is2 ? wt2f : wt3f;
        for (int it = 0; it < 18; ++it) {
            int i = tid + it * 256;            // 4608 = 8*2304/4
            float4 v = *(const float4*)(src + i * 4);
            int n = i / 576, t4 = (i % 576) * 4;
            L[n * 2304 + t4 + 0] = f2bf(v.x);
            L[n * 2304 + t4 + 1] = f2bf(v.y);
            L[n * 2304 + t4 + 2] = f2bf(v.z);
            L[n * 2304 + t4 + 3] = f2bf(v.w);
        }
        __syncthreads();
        for (int it = 0; it < 9; ++it) {
            int v = tid + it * 256;            // 2304 = 16*9*2*8
            int o8 = v & 7; int rest = v >> 3;
            int half = rest & 1; rest >>= 1;
            int tap = rest % 9; int icb = rest / 9;
            int lane = half * 32 + nb + o8;
            u16x8 pk;
            #pragma unroll
            for (int j = 0; j < 8; ++j) {
                int ic = icb * 16 + half * 8 + j;
                pk[j] = L[o8 * 2304 + ic * 9 + tap];
            }
            size_t dest = ((((size_t)(ocb * 16 + icb) * 9 + tap) * 4 + ot) * 64 + lane) * 8;
            *(u16x8*)&dst[dest] = pk;
        }
    } else if (blk < 312) {
        // head weights: block = 1 oc. 6468 fp32 -> wtHt[oc][6272], r = s*128+c
        const int oc = blk - 56;
        const float* src = hw + (size_t)oc * KHEAD;
        for (int it = 0; it < 7; ++it) {
            int i = tid + it * 256;
            if (i < 1617) {
                float4 v = *(const float4*)(src + i * 4);
                L[i * 4 + 0] = f2bf(v.x);
                L[i * 4 + 1] = f2bf(v.y);
                L[i * 4 + 2] = f2bf(v.z);
                L[i * 4 + 3] = f2bf(v.w);
            }
        }
        if (tid < 4) {
            const float* p = src + (128 + tid) * 49;
            float s = 0.f;
            #pragma unroll
            for (int t = 0; t < 49; ++t) s += p[t];
            wsum4[oc * 4 + tid] = s;
        }
        __syncthreads();
        for (int it = 0; it < 4; ++it) {
            int v = tid + it * 256;
            if (v >= 784) break;               // 6272/8
            u16x8 pk;
            #pragma unroll
            for (int j = 0; j < 8; ++j) {
                int r = v * 8 + j;
                int s = r >> 7, c = r & 127;
                pk[j] = L[c * 49 + s];
            }
            *(u16x8*)&wtHt[(size_t)oc * KRF + v * 8] = pk;
        }
    } else if (blk < 344) {
        const bool is6 = blk < 328;
        const int b = is6 ? (blk - 312) : (blk - 328);
        const float* src = (is6 ? f6w : f7w) + (size_t)(b * 256 + tid) * 16;
        u16* dst = (is6 ? w6c : w7c) + (size_t)(b * 256 + tid) * 16;
        u16x8 pk0, pk1;
        #pragma unroll
        for (int h = 0; h < 2; ++h) {
            float4 v0 = *(const float4*)(src + h * 8);
            float4 v1 = *(const float4*)(src + h * 8 + 4);
            u16x8 pk;
            pk[0] = f2bf(v0.x); pk[1] = f2bf(v0.y); pk[2] = f2bf(v0.z); pk[3] = f2bf(v0.w);
            pk[4] = f2bf(v1.x); pk[5] = f2bf(v1.y); pk[6] = f2bf(v1.z); pk[7] = f2bf(v1.w);
            if (h == 0) pk0 = pk; else pk1 = pk;
        }
        *(u16x8*)(dst + 0) = pk0;
        *(u16x8*)(dst + 8) = pk1;
    } else {
        // zero halo ring of act1p/act2p
        int idx = (blk - 344) * 256 + tid;     // 99328 total
        int c8 = idx & 31;
        int t = idx >> 5;
        int h = t % 388, img = t / 388;
        u16* base = (img & 4) ? a2 : a1;
        int b = img & 3;
        int y, x;
        if (h < 98)       { y = 0;  x = h; }
        else if (h < 196) { y = 97; x = h - 98; }
        else { int r = (h - 196) >> 1; x = ((h - 196) & 1) * 97; y = 1 + r; }
        long long off = (((long long)(b * 98 + y)) * 98 + x) * 256 + c8 * 8;
        i32x4 z = {0, 0, 0, 0};
        *(i32x4*)(base + off) = z;
    }
}

// ---------------------------------------------------------------------------
// conv1 (1x1, K=324->352) fused fp32 transpose + 32x32x16 MFMA.
__global__ __launch_bounds__(256) void conv1_v2(
    const float* __restrict__ corr, const u16* __restrict__ wf,
    const float* __restrict__ bias, u16* __restrict__ outp)
{
    __shared__ __align__(16) u16 Ws1[8192];
    __shared__ __align__(16) u16 Bs[64 * 40];
    const int tid = threadIdx.x;
    const int b = blockIdx.y;
    const int p0 = blockIdx.x * 64;
    const int lane = tid & 63, wid = tid >> 6;
    const int n = lane & 31, half = lane >> 5;
    const int wocw = wid & 1, wpx = wid >> 1;
    const int kr = tid >> 3, pxg = tid & 7;

    f32x16 acc[4];
    #pragma unroll
    for (int i = 0; i < 4; ++i)
        #pragma unroll
        for (int e = 0; e < 16; ++e) acc[i][e] = 0.f;

    float4 s0 = {0,0,0,0}, s1 = {0,0,0,0};
    if (kr < C0) {
        const float* src = &corr[((long long)(b * C0 + kr)) * PIX + p0 + pxg * 8];
        s0 = *(const float4*)src; s1 = *(const float4*)(src + 4);
    }
    bf16x8 wr[4];
    #pragma unroll
    for (int i = 0; i < 4; ++i) wr[i] = *(const bf16x8*)(wf + (i * 256 + tid) * 8);

    for (int kc = 0; kc < 11; ++kc) {
        __syncthreads();
        Bs[(pxg * 8 + 0) * 40 + kr] = f2bf(s0.x);
        Bs[(pxg * 8 + 1) * 40 + kr] = f2bf(s0.y);
        Bs[(pxg * 8 + 2) * 40 + kr] = f2bf(s0.z);
        Bs[(pxg * 8 + 3) * 40 + kr] = f2bf(s0.w);
        Bs[(pxg * 8 + 4) * 40 + kr] = f2bf(s1.x);
        Bs[(pxg * 8 + 5) * 40 + kr] = f2bf(s1.y);
        Bs[(pxg * 8 + 6) * 40 + kr] = f2bf(s1.z);
        Bs[(pxg * 8 + 7) * 40 + kr] = f2bf(s1.w);
        #pragma unroll
        for (int i = 0; i < 4; ++i) *(bf16x8*)&Ws1[(i * 256 + tid) * 8] = wr[i];
        __syncthreads();
        if (kc < 10) {
            int k = (kc + 1) * 32 + kr;
            if (k < C0) {
                const float* src = &corr[((long long)(b * C0 + k)) * PIX + p0 + pxg * 8];
                s0 = *(const float4*)src; s1 = *(const float4*)(src + 4);
            } else { s0 = (float4){0,0,0,0}; s1 = (float4){0,0,0,0}; }
            const u16* wn = wf + (kc + 1) * 8192;
            #pragma unroll
            for (int i = 0; i < 4; ++i) wr[i] = *(const bf16x8*)(wn + (i * 256 + tid) * 8);
        }
        #pragma unroll
        for (int ks = 0; ks < 2; ++ks) {
            bf16x8 bb = *(const bf16x8*)&Bs[(wpx * 32 + n) * 40 + ks * 16 + half * 8];
            #pragma unroll
            for (int ot = 0; ot < 4; ++ot) {
                bf16x8 a = *(const bf16x8*)&Ws1[((ks * 8 + wocw * 4 + ot) * 64 + lane) * 8];
                acc[ot] = __builtin_amdgcn_mfma_f32_32x32x16_bf16(a, bb, acc[ot], 0, 0, 0);
            }
        }
    }
    const int px = p0 + wpx * 32 + n;
    const int y = px / 96, x = px % 96;
    const long long obase = (((long long)(b * 98 + y + 1)) * 98 + x + 1) * 256;
    #pragma unroll
    for (int ot = 0; ot < 4; ++ot) {
        int ocb = wocw * 128 + ot * 32;
        f32x16 d = acc[ot];
        #pragma unroll
        for (int r2 = 0; r2 < 4; ++r2) {
            int oc4 = ocb + r2 * 8 + half * 4;
            f32x4 bv = *(const f32x4*)(bias + oc4);
            u16x4 pk;
            #pragma unroll
            for (int g = 0; g < 4; ++g) pk[g] = f2bf(fmaxf(d[r2 * 4 + g] + bv[g], 0.f));
            *(u16x4*)(outp + obase + oc4) = pk;
        }
    }
}

// ---------------------------------------------------------------------------
// conv3x3 32x32x16 MFMA, v3: per stage ALL fragments hoisted to registers
// (18 A + 12 B ds_read_b128 burst, then 36 MFMAs in 4 independent chains).
template<int COUT, bool PADOUT>
__global__ __launch_bounds__(256, 2) void conv3x3_v3(
    const u16* __restrict__ inp, const u16* __restrict__ wf,
    const float* __restrict__ bias, u16* __restrict__ outp)
{
    __shared__ __align__(16) u16 Ws[CWSTG];      // [tap9][ot4][lane64][8]
    __shared__ __align__(16) u16 Hs[204 * 24];   // [row6][col34][ic16 pad24]
    const int tid = threadIdx.x;
    const int b = blockIdx.z;
    const int x0 = (blockIdx.x % 3) * 32, y0 = (blockIdx.x / 3) * 4;
    const int lane = tid & 63, wid = tid >> 6;
    const int n = lane & 31, half = lane >> 5;
    const int woc = wid & 1, wpx = wid >> 1;

    const u16* wsrc = wf + (size_t)blockIdx.y * 16 * CWSTG;
    const bool hstager = tid < 204;
    const int hrow = tid / 34, hcol = tid % 34;
    const u16* hsrc = inp + (((size_t)(b * 98 + y0 + hrow)) * 98 + x0 + hcol) * 256;

    f32x16 acc[2][2];
    #pragma unroll
    for (int i = 0; i < 2; ++i)
        #pragma unroll
        for (int r = 0; r < 2; ++r)
            #pragma unroll
            for (int e = 0; e < 16; ++e) acc[i][r][e] = 0.f;

    bf16x8 wreg[9];
    bf16x8 h0, h1;
    #pragma unroll
    for (int it = 0; it < 9; ++it)
        wreg[it] = *(const bf16x8*)(wsrc + (it * 256 + tid) * 8);
    if (hstager) { h0 = *(const bf16x8*)hsrc; h1 = *(const bf16x8*)(hsrc + 8); }

    for (int icb = 0; icb < 16; ++icb) {
        __syncthreads();
        #pragma unroll
        for (int it = 0; it < 9; ++it)
            *(bf16x8*)&Ws[(it * 256 + tid) * 8] = wreg[it];
        if (hstager) {
            *(bf16x8*)&Hs[tid * 24]     = h0;
            *(bf16x8*)&Hs[tid * 24 + 8] = h1;
        }
        __syncthreads();
        if (icb < 15) {
            const u16* wn = wsrc + (size_t)(icb + 1) * CWSTG;
            #pragma unroll
            for (int it = 0; it < 9; ++it)
                wreg[it] = *(const bf16x8*)(wn + (it * 256 + tid) * 8);
            if (hstager) {
                const u16* hn = hsrc + (icb + 1) * 16;
                h0 = *(const bf16x8*)hn; h1 = *(const bf16x8*)(hn + 8);
            }
        }
        // hoist all fragments for this stage
        bf16x8 afr[9][2];
        #pragma unroll
        for (int tap = 0; tap < 9; ++tap)
            #pragma unroll
            for (int j = 0; j < 2; ++j)
                afr[tap][j] = *(const bf16x8*)&Ws[((tap * 4 + woc * 2 + j) * 64 + lane) * 8];
        bf16x8 bfr[4][3];
        #pragma unroll
        for (int rr = 0; rr < 4; ++rr)
            #pragma unroll
            for (int dx = 0; dx < 3; ++dx)
                bfr[rr][dx] = *(const bf16x8*)&Hs[((wpx * 2 + rr) * 34 + dx + n) * 24 + half * 8];
        #pragma unroll
        for (int tap = 0; tap < 9; ++tap) {
            const int dy = tap / 3, dx = tap % 3;
            #pragma unroll
            for (int r = 0; r < 2; ++r) {
                acc[0][r] = __builtin_amdgcn_mfma_f32_32x32x16_bf16(afr[tap][0], bfr[r + dy][dx], acc[0][r], 0, 0, 0);
                acc[1][r] = __builtin_amdgcn_mfma_f32_32x32x16_bf16(afr[tap][1], bfr[r + dy][dx], acc[1][r], 0, 0, 0);
            }
        }
    }
    #pragma unroll
    for (int ot = 0; ot < 2; ++ot) {
        int ocb = blockIdx.y * 128 + woc * 64 + ot * 32;
        #pragma unroll
        for (int r = 0; r < 2; ++r) {
            int y = y0 + wpx * 2 + r;
            int x = x0 + n;
            f32x16 d = acc[ot][r];
            long long obase;
            if (PADOUT) obase = (((long long)(b * 98 + y + 1)) * 98 + x + 1) * COUT;
            else        obase = (((long long)(b * 96 + y)) * 96 + x) * COUT;
            #pragma unroll
            for (int r2 = 0; r2 < 4; ++r2) {
                int oc4 = ocb + r2 * 8 + half * 4;
                f32x4 bv = *(const f32x4*)(bias + oc4);
                u16x4 pk;
                #pragma unroll
                for (int g = 0; g < 4; ++g) pk[g] = f2bf(fmaxf(d[r2 * 4 + g] + bv[g], 0.f));
                *(u16x4*)(outp + obase + oc4) = pk;
            }
        }
    }
}

// ---------------------------------------------------------------------------
// ROI align: rel [4][96][96][128] bf16 -> rf [192][6272] bf16 (k' = s*128+c)
__global__ __launch_bounds__(256) void roi_align_cl(
    const u16* __restrict__ rel, const float* __restrict__ det1,
    u16* __restrict__ rf)
{
    const int roi = blockIdx.x, tid = threadIdx.x;
    const int c = tid & 127, sb = tid >> 7;
    const int b = roi / MM, m = roi % MM;
    const float* d = det1 + (long long)(b * MM + m) * 10;
    float cx = d[2], cy = d[3], w = d[4], h = d[5];
    float x1f = cx - w * 0.5f, y1f = cy - h * 0.5f;
    float x1 = x1f * 0.125f, y1 = y1f * 0.125f;
    float x2 = (x1f + w) * 0.125f, y2 = (y1f + h) * 0.125f;
    float bh = (y2 - y1) * (1.f / 7.f), bw = (x2 - x1) * (1.f / 7.f);
    const u16* fb = rel + (long long)b * PIX * 128 + c;
    for (int s = sb; s < 49; s += 2) {
        int i = s / 7, j = s % 7;
        float sum = 0.f;
        #pragma unroll
        for (int di = 0; di < 2; ++di) {
            float y = y1 + ((float)(2 * i + di) + 0.5f) * 0.5f * bh;
            y = fminf(fmaxf(y, 0.f), 95.f);
            int yy0 = (int)floorf(y);
            int yy1 = min(yy0 + 1, 95);
            float wy = y - (float)yy0;
            #pragma unroll
            for (int dj = 0; dj < 2; ++dj) {
                float x = x1 + ((float)(2 * j + dj) + 0.5f) * 0.5f * bw;
                x = fminf(fmaxf(x, 0.f), 95.f);
                int xx0 = (int)floorf(x);
                int xx1 = min(xx0 + 1, 95);
                float wx = x - (float)xx0;
                float f00 = b2f(fb[((long long)yy0 * 96 + xx0) * 128]);
                float f01 = b2f(fb[((long long)yy0 * 96 + xx1) * 128]);
                float f10 = b2f(fb[((long long)yy1 * 96 + xx0) * 128]);
                float f11 = b2f(fb[((long long)yy1 * 96 + xx1) * 128]);
                sum += f00 * (1.f - wy) * (1.f - wx) + f01 * (1.f - wy) * wx
                     + f10 * wy * (1.f - wx) + f11 * wy * wx;
            }
        }
        rf[(long long)roi * KRF + s * 128 + c] = f2bf(sum * 0.25f);
    }
}

// ---------------------------------------------------------------------------
// Head GEMM split-K (28 splits x 7 chunks). Block 64 rois x 128 oc. Grid (6,28).
__global__ __launch_bounds__(256) void head_gemm_mfma(
    const u16* __restrict__ rf, const u16* __restrict__ wtHt,
    float* __restrict__ Gpart)
{
    __shared__ __align__(16) u16 As[64 * 40];
    __shared__ __align__(16) u16 Bs[128 * 40];
    const int tid = threadIdx.x;
    const int rb = blockIdx.x >> 1, ob = blockIdx.x & 1;
    const int split = blockIdx.y;
    const int lane = tid & 63, wid = tid >> 6;
    const int q = lane >> 4, m16 = lane & 15;
    const int wr = wid & 1, wo = wid >> 1;

    const int arl = tid >> 2, aqd = tid & 3;
    const u16* abase = rf + (long long)(rb * 64 + arl) * KRF + aqd * 8;
    const int bol0 = tid >> 2, bqd = tid & 3;
    const u16* bbase0 = wtHt + (long long)(ob * 128 + bol0) * KRF + bqd * 8;
    const u16* bbase1 = bbase0 + 64LL * KRF;

    f32x4 acc[2][4];
    #pragma unroll
    for (int i = 0; i < 2; ++i)
        #pragma unroll
        for (int j = 0; j < 4; ++j) acc[i][j] = (f32x4){0.f, 0.f, 0.f, 0.f};

    int k0 = split * CPS * 32;
    bf16x8 ra = *(const bf16x8*)(abase + k0);
    bf16x8 rb0 = *(const bf16x8*)(bbase0 + k0);
    bf16x8 rb1 = *(const bf16x8*)(bbase1 + k0);
    for (int cch = 0; cch < CPS; ++cch) {
        __syncthreads();
        *(bf16x8*)&As[arl * 40 + aqd * 8] = ra;
        *(bf16x8*)&Bs[bol0 * 40 + bqd * 8] = rb0;
        *(bf16x8*)&Bs[(64 + bol0) * 40 + bqd * 8] = rb1;
        __syncthreads();
        if (cch < CPS - 1) {
            int kn = k0 + (cch + 1) * 32;
            ra  = *(const bf16x8*)(abase + kn);
            rb0 = *(const bf16x8*)(bbase0 + kn);
            rb1 = *(const bf16x8*)(bbase1 + kn);
        }
        bf16x8 a[2], bb[4];
        #pragma unroll
        for (int rt = 0; rt < 2; ++rt)
            a[rt] = *(const bf16x8*)&As[(wr * 32 + rt * 16 + m16) * 40 + q * 8];
        #pragma unroll
        for (int ot = 0; ot < 4; ++ot)
            bb[ot] = *(const bf16x8*)&Bs[(wo * 64 + ot * 16 + m16) * 40 + q * 8];
        #pragma unroll
        for (int rt = 0; rt < 2; ++rt)
            #pragma unroll
            for (int ot = 0; ot < 4; ++ot)
                acc[rt][ot] = __builtin_amdgcn_mfma_f32_16x16x32_bf16(a[rt], bb[ot], acc[rt][ot], 0, 0, 0);
    }
    #pragma unroll
    for (int rt = 0; rt < 2; ++rt)
        #pragma unroll
        for (int ot = 0; ot < 4; ++ot) {
            int oc = ob * 128 + wo * 64 + ot * 16 + m16;
            #pragma unroll
            for (int rg = 0; rg < 4; ++rg) {
                int roi = rb * 64 + wr * 32 + rt * 16 + q * 4 + rg;
                Gpart[((long long)split * NROI + roi) * 256 + oc] = acc[rt][ot][rg];
            }
        }
}

// ---------------------------------------------------------------------------
// Fused tail: Gpart reduction + pair geometry + build_X + fc6 + fc7 + cls.
#define PHS 272
__global__ __launch_bounds__(256) void pair_head(
    const float* __restrict__ Gpart, const float* __restrict__ d1,
    const float* __restrict__ d2, const float* __restrict__ wsum4,
    const float* __restrict__ hb,
    const u16* __restrict__ w6, const float* __restrict__ b6,
    const u16* __restrict__ w7, const float* __restrict__ b7,
    const float* __restrict__ cw, const float* __restrict__ cb,
    float* __restrict__ scores, float* __restrict__ labels,
    float* __restrict__ valid)
{
    __shared__ __align__(16) u16 bufA[64 * PHS];
    __shared__ __align__(16) u16 bufB[64 * PHS];
    __shared__ float Gs[2][256];
    __shared__ float ps[64][4];
    __shared__ float clw[256];

    const int tid = threadIdx.x;
    const int p0 = blockIdx.x * 64;
    const int r0 = p0 / MM;
    const int lane = tid & 63, w = tid >> 6;
    const int q = lane >> 4, m16 = lane & 15;

    clw[tid] = cw[tid];
    #pragma unroll
    for (int l = 0; l < 2; ++l) {
        int idx = tid + l * 256;
        int rr = idx >> 8, col = idx & 255;
        int roi = min(r0 + rr, NROI - 1);
        float s = 0.f;
        #pragma unroll
        for (int sp = 0; sp < SPLITS; ++sp)
            s += Gpart[((long long)sp * NROI + roi) * 256 + col];
        Gs[rr][col] = s;
    }
    if (tid < 64) {
        int pair = p0 + tid;
        int b = pair / (MM * MM); int rem = pair % (MM * MM);
        int m1 = rem / MM, m2 = rem % MM;
        const float* rA = d1 + (long long)(b * MM + m1) * 10;
        const float* rB = d2 + (long long)(b * MM + m2) * 10;
        float v1 = rA[0], id1 = rA[1], cxa = rA[2], cya = rA[3], wa = rA[4], ha = rA[5];
        float v2 = rB[0], id2 = rB[1], cxb = rB[2], cyb = rB[3], wb = rB[4], hbv = rB[5];
        const float eps = 1e-6f;
        float ax1 = cxa - wa * 0.5f, ay1 = cya - ha * 0.5f;
        float ax2 = ax1 + wa,        ay2 = ay1 + ha;
        float bx1 = cxb - wb * 0.5f, by1 = cyb - hbv * 0.5f;
        float bx2 = bx1 + wb,        by2 = by1 + hbv;
        float ccx1 = (ax1 + ax2) * 0.5f, ccy1 = (ay1 + ay2) * 0.5f;
        float ww1 = fmaxf(ax2 - ax1, eps), hh1 = fmaxf(ay2 - ay1, eps);
        float ccx2 = (bx1 + bx2) * 0.5f, ccy2 = (by1 + by2) * 0.5f;
        float ww2 = fmaxf(bx2 - bx1, eps), hh2 = fmaxf(by2 - by1, eps);
        ps[tid][0] = (ccx2 - ccx1) / ww1;
        ps[tid][1] = (ccy2 - ccy1) / hh1;
        ps[tid][2] = logf(ww2 / ww1);
        ps[tid][3] = logf(hh2 / hh1);
        labels[pair] = (id1 == id2) ? 1.f : 0.f;
        valid[pair]  = (v1 != -1.f && v2 != -1.f) ? 1.f : 0.f;
    }
    __syncthreads();

    #pragma unroll
    for (int it = 0; it < 16; ++it) {
        int idx = tid + it * 256;
        int px = idx >> 6, o4 = (idx & 63) * 4;
        int rl = (p0 + px) / MM - r0;
        f32x4 g = *(const f32x4*)&Gs[rl][o4];
        f32x4 hv = *(const f32x4*)&hb[o4];
        f32x4 p4 = *(const f32x4*)&ps[px][0];
        u16x4 pk;
        #pragma unroll
        for (int j = 0; j < 4; ++j) {
            f32x4 w4 = *(const f32x4*)&wsum4[(o4 + j) * 4];
            float v = g[j] + hv[j] + p4[0] * w4[0] + p4[1] * w4[1] + p4[2] * w4[2] + p4[3] * w4[3];
            pk[j] = f2bf(v);
        }
        *(u16x4*)&bufA[px * PHS + o4] = pk;
    }
    __syncthreads();

    #pragma unroll
    for (int layer = 0; layer < 2; ++layer) {
        const u16* wgt = layer ? w7 : w6;
        const float* bs = layer ? b7 : b6;
        const u16* src = layer ? bufB : bufA;
        u16* dst = layer ? bufA : bufB;
        f32x4 acc[4][4];
        #pragma unroll
        for (int i = 0; i < 4; ++i)
            #pragma unroll
            for (int j = 0; j < 4; ++j) acc[i][j] = (f32x4){0.f, 0.f, 0.f, 0.f};
        #pragma unroll
        for (int kc = 0; kc < 8; ++kc) {
            bf16x8 a[4], bb[4];
            #pragma unroll
            for (int i = 0; i < 4; ++i)
                a[i] = *(const bf16x8*)&wgt[(w * 64 + i * 16 + m16) * 256 + kc * 32 + q * 8];
            #pragma unroll
            for (int pt = 0; pt < 4; ++pt)
                bb[pt] = *(const bf16x8*)&src[(pt * 16 + m16) * PHS + kc * 32 + q * 8];
            #pragma unroll
            for (int i = 0; i < 4; ++i)
                #pragma unroll
                for (int pt = 0; pt < 4; ++pt)
                    acc[i][pt] = __builtin_amdgcn_mfma_f32_16x16x32_bf16(a[i], bb[pt], acc[i][pt], 0, 0, 0);
        }
        #pragma unroll
        for (int i = 0; i < 4; ++i) {
            int oc4 = w * 64 + i * 16 + q * 4;
            f32x4 bv = *(const f32x4*)(bs + oc4);
            #pragma unroll
            for (int pt = 0; pt < 4; ++pt) {
                int px = pt * 16 + m16;
                f32x4 dd = acc[i][pt];
                u16x4 pk;
                #pragma unroll
                for (int rg = 0; rg < 4; ++rg)
                    pk[rg] = f2bf(fmaxf(dd[rg] + bv[rg], 0.f));
                *(u16x4*)&dst[px * PHS + oc4] = pk;
            }
        }
        __syncthreads();
    }

    {
        int px = tid >> 2, qq = tid & 3;
        float acc = 0.f;
        #pragma unroll
        for (int k8 = 0; k8 < 8; ++k8) {
            bf16x8 hv = *(const bf16x8*)&bufA[px * PHS + qq * 64 + k8 * 8];
            #pragma unroll
            for (int e = 0; e < 8; ++e)
                acc += b2f((u16)hv[e]) * clw[qq * 64 + k8 * 8 + e];
        }
        acc += __shfl_xor(acc, 1, 64);
        acc += __shfl_xor(acc, 2, 64);
        if (qq == 0) scores[p0 + px] = acc + cb[0];
    }
}

// ---------------------------------------------------------------------------
extern "C" void kernel_launch(void* const* d_in, const int* in_sizes, int n_in,
                              void* d_out, int out_size, void* d_ws, size_t ws_size,
                              hipStream_t stream) {
    const float* corr   = (const float*)d_in[0];
    const float* det1   = (const float*)d_in[2];
    const float* det2   = (const float*)d_in[3];
    const float* c1w    = (const float*)d_in[4];
    const float* c1b    = (const float*)d_in[5];
    const float* c2w    = (const float*)d_in[6];
    const float* c2b    = (const float*)d_in[7];
    const float* c3w    = (const float*)d_in[8];
    const float* c3b    = (const float*)d_in[9];
    const float* hw     = (const float*)d_in[10];
    const float* hbias  = (const float*)d_in[11];
    const float* f6w    = (const float*)d_in[12];
    const float* f6b    = (const float*)d_in[13];
    const float* f7w    = (const float*)d_in[14];
    const float* f7b    = (const float*)d_in[15];
    const float* clsw   = (const float*)d_in[16];
    const float* clsb   = (const float*)d_in[17];
    float* out = (float*)d_out;

    char* base = (char*)d_ws;
    auto alloc = [&](size_t bytes) { char* p = base; base += (bytes + 255) & ~(size_t)255; return p; };

    const size_t ACTP_BYTES = (size_t)NB * 98 * 98 * 256 * 2;
    u16*   act1p = (u16*)  alloc(ACTP_BYTES);
    u16*   act2p = (u16*)  alloc(ACTP_BYTES);
    u16*   rel   = (u16*)  alloc((size_t)NB * PIX * 128 * 2);
    u16*   wt1f  = (u16*)  alloc((size_t)90112 * 2);
    u16*   wt2f  = (u16*)  alloc((size_t)2 * 16 * CWSTG * 2);
    u16*   wt3f  = (u16*)  alloc((size_t)16 * CWSTG * 2);
    u16*   wtHt  = (u16*)  alloc((size_t)256 * KRF * 2);
    u16*   w6c   = (u16*)  alloc(256 * 256 * 2);
    u16*   w7c   = (u16*)  alloc(256 * 256 * 2);
    float* wsum4 = (float*)alloc(256 * 4 * 4);
    u16*   rf    = (u16*)  alloc((size_t)NROI * KRF * 2);
    float* Gpart = (float*)alloc((size_t)SPLITS * NROI * 256 * 4);

    float* scores_out = out;
    float* labels_out = out + NPAIR;
    float* valid_out  = out + 2 * NPAIR;

    prep_v2<<<732, 256, 0, stream>>>(c1w, c2w, c3w, hw, f6w, f7w,
                                     wt1f, wt2f, wt3f, wtHt, w6c, w7c, wsum4,
                                     act1p, act2p);
    conv1_v2<<<dim3(144, NB), 256, 0, stream>>>(corr, wt1f, c1b, act1p);
    conv3x3_v3<256, true><<<dim3(72, 2, NB), 256, 0, stream>>>(act1p, wt2f, c2b, act2p);
    conv3x3_v3<128, false><<<dim3(72, 1, NB), 256, 0, stream>>>(act2p, wt3f, c3b, rel);
    roi_align_cl<<<NROI, 256, 0, stream>>>(rel, det1, rf);
    head_gemm_mfma<<<dim3(6, SPLITS), 256, 0, stream>>>(rf, wtHt, Gpart);
    pair_head<<<144, 256, 0, stream>>>(Gpart, det1, det2, wsum4, hbias,
                                       w6c, f6b, w7c, f7b, clsw, clsb,
                                       scores_out, labels_out, valid_out);
}